// Round 1
// baseline (9687.585 us; speedup 1.0000x reference)
//
#include <hip/hip_runtime.h>
#include <math.h>

#define NN 100000
#define NE 1600000
#define NG 1000
#define IN_DIM 64
#define HID 128
#define EXD 32
#define OUTD 10
#define BN_EPS 1e-5f

// ---------------- degree / normalization (layer-invariant) ----------------

__global__ void deg_kernel(const int* __restrict__ dst, float* __restrict__ deg) {
    int e = blockIdx.x * 256 + threadIdx.x;
    if (e < NE) atomicAdd(&deg[dst[e]], 1.0f);
}

__global__ void dinv_kernel(const float* __restrict__ deg, float* __restrict__ dinv) {
    int i = blockIdx.x * 256 + threadIdx.x;
    if (i < NN) dinv[i] = rsqrtf(deg[i] + 1.0f);   // +1 self loop
}

__global__ void coef_kernel(const int* __restrict__ src, const int* __restrict__ dst,
                            const float* __restrict__ dinv, float* __restrict__ coef) {
    int e = blockIdx.x * 256 + threadIdx.x;
    if (e < NE) coef[e] = dinv[src[e]] * dinv[dst[e]];
}

__global__ void cnt_kernel(const int* __restrict__ batch, float* __restrict__ cnt) {
    int n = blockIdx.x * 256 + threadIdx.x;
    if (n < NN) atomicAdd(&cnt[batch[n]], 1.0f);
}

// ---------------- GCN aggregation ----------------

// agg[n,f] = xw[n,f] * dinv[n]^2 + b[f]   (self-loop term + bias)
__global__ void agg_init_kernel(const float* __restrict__ xw, const float* __restrict__ dinv,
                                const float* __restrict__ b, float* __restrict__ agg) {
    int i = blockIdx.x * 256 + threadIdx.x;       // over NN*32 float4s
    if (i >= NN * 32) return;
    int n = i >> 5, c = (i & 31) << 2;
    float d = dinv[n]; float d2 = d * d;
    float4 v = *(const float4*)(xw + (size_t)i * 4);
    float4 r;
    r.x = v.x * d2 + b[c + 0];
    r.y = v.y * d2 + b[c + 1];
    r.z = v.z * d2 + b[c + 2];
    r.w = v.w * d2 + b[c + 3];
    *(float4*)(agg + (size_t)i * 4) = r;
}

// agg[dst] += xw[src] * coef   (32 threads per edge, float4 each)
__global__ void scatter_kernel(const int* __restrict__ src, const int* __restrict__ dst,
                               const float* __restrict__ coef,
                               const float* __restrict__ xw, float* __restrict__ agg) {
    int i = blockIdx.x * 256 + threadIdx.x;       // over NE*32
    if (i >= NE * 32) return;
    int e = i >> 5, c = (i & 31) << 2;
    int s = src[e], d = dst[e];
    float cf = coef[e];
    float4 v = *(const float4*)(xw + (size_t)s * HID + c);
    float* p = agg + (size_t)d * HID + c;
    atomicAdd(p + 0, v.x * cf);
    atomicAdd(p + 1, v.y * cf);
    atomicAdd(p + 2, v.z * cf);
    atomicAdd(p + 3, v.w * cf);
}

// ---------------- BatchNorm ----------------

__global__ void bn_stats_kernel(const float* __restrict__ agg,
                                float* __restrict__ gsum, float* __restrict__ gsq) {
    __shared__ float ss[256], sq[256];
    int t = threadIdx.x;
    int f = t & 127;
    int sub = t >> 7;
    float s = 0.f, q = 0.f;
    for (int r = blockIdx.x * 2 + sub; r < NN; r += gridDim.x * 2) {
        float v = agg[(size_t)r * HID + f];
        s += v; q += v * v;
    }
    ss[t] = s; sq[t] = q;
    __syncthreads();
    if (t < 128) {
        atomicAdd(&gsum[f], ss[t] + ss[t + 128]);
        atomicAdd(&gsq[f],  sq[t] + sq[t + 128]);
    }
}

__global__ void bn_finalize_kernel(const float* __restrict__ gsum, const float* __restrict__ gsq,
                                   const float* __restrict__ g, const float* __restrict__ be,
                                   float* __restrict__ scale, float* __restrict__ shift) {
    int f = threadIdx.x;
    float mu = gsum[f] * (1.0f / NN);
    float var = gsq[f] * (1.0f / NN) - mu * mu;
    float sc = g[f] * rsqrtf(var + BN_EPS);
    scale[f] = sc;
    shift[f] = be[f] - mu * sc;
}

// out_x = relu(bn(agg)) in place
__global__ void bn_apply_relu_kernel(float* __restrict__ agg,
                                     const float* __restrict__ scale,
                                     const float* __restrict__ shift) {
    int i = blockIdx.x * 256 + threadIdx.x;       // over NN*32 float4s
    if (i >= NN * 32) return;
    int c = (i & 31) << 2;
    float4 v = *(const float4*)(agg + (size_t)i * 4);
    v.x = fmaxf(v.x * scale[c + 0] + shift[c + 0], 0.f);
    v.y = fmaxf(v.y * scale[c + 1] + shift[c + 1], 0.f);
    v.z = fmaxf(v.z * scale[c + 2] + shift[c + 2], 0.f);
    v.w = fmaxf(v.w * scale[c + 3] + shift[c + 3], 0.f);
    *(float4*)(agg + (size_t)i * 4) = v;
}

// ---------------- GEMM (f32, register-tiled 64 nodes x 128 outs) ----------------
// mode 0: target[n,:] = A1 @ Wa                  (K1 in {64,128})
// mode 1: t = A1@Wa + bias1 + A2@Wb + bias2; z = sigmoid(t);
//         target[n,o] = z*outx[n,o] + (1-z)*target[n,o]   (target aliases A2)
__launch_bounds__(256)
__global__ void gemm_kernel(const float* __restrict__ A1, const float* __restrict__ Wa, int K1,
                            const float* A2, const float* __restrict__ Wb, int K2,
                            const float* __restrict__ bias1, const float* __restrict__ bias2,
                            const float* __restrict__ outx, float* target, int mode) {
    __shared__ float As[64][17];
    __shared__ float Ws[16][128];
    int tid = threadIdx.x;
    int n0 = blockIdx.x * 64;
    int to = tid & 15;          // outputs ob..ob+7
    int tn = tid >> 4;          // nodes n0 + tn*4 .. +3
    int ob = to << 3;
    int tn4 = tn << 2;

    float acc[4][8];
#pragma unroll
    for (int i = 0; i < 4; ++i)
#pragma unroll
        for (int j = 0; j < 8; ++j) acc[i][j] = 0.f;

    int r  = tid >> 2;          // A-staging row 0..63
    int cc = (tid & 3) << 2;    // A-staging col 0,4,8,12
    int kr = tid >> 4;          // W-staging row 0..15
    int oo = (tid & 15) << 3;   // W-staging col 0..120

    for (int pass = 0; pass < 2; ++pass) {
        const float* A = pass ? A2 : A1;
        const float* W = pass ? Wb : Wa;
        int K = pass ? K2 : K1;
        if (K == 0) break;
        for (int k0 = 0; k0 < K; k0 += 16) {
            int n = n0 + r;
            float4 av = make_float4(0.f, 0.f, 0.f, 0.f);
            if (n < NN) av = *(const float4*)(A + (size_t)n * K + k0 + cc);
            As[r][cc + 0] = av.x; As[r][cc + 1] = av.y;
            As[r][cc + 2] = av.z; As[r][cc + 3] = av.w;
            float4 w0 = *(const float4*)(W + (size_t)(k0 + kr) * HID + oo);
            float4 w1 = *(const float4*)(W + (size_t)(k0 + kr) * HID + oo + 4);
            *(float4*)&Ws[kr][oo]     = w0;
            *(float4*)&Ws[kr][oo + 4] = w1;
            __syncthreads();
#pragma unroll
            for (int k = 0; k < 16; ++k) {
                float a[4];
                a[0] = As[tn4 + 0][k]; a[1] = As[tn4 + 1][k];
                a[2] = As[tn4 + 2][k]; a[3] = As[tn4 + 3][k];
                float4 w0v = *(const float4*)&Ws[k][ob];
                float4 w1v = *(const float4*)&Ws[k][ob + 4];
                float w[8] = {w0v.x, w0v.y, w0v.z, w0v.w, w1v.x, w1v.y, w1v.z, w1v.w};
#pragma unroll
                for (int i = 0; i < 4; ++i)
#pragma unroll
                    for (int j = 0; j < 8; ++j) acc[i][j] += a[i] * w[j];
            }
            __syncthreads();
        }
    }

    if (mode == 0) {
#pragma unroll
        for (int i = 0; i < 4; ++i) {
            int n = n0 + tn4 + i;
            if (n >= NN) continue;
            float* p = target + (size_t)n * HID + ob;
            float4 r0 = make_float4(acc[i][0], acc[i][1], acc[i][2], acc[i][3]);
            float4 r1 = make_float4(acc[i][4], acc[i][5], acc[i][6], acc[i][7]);
            *(float4*)p = r0;
            *(float4*)(p + 4) = r1;
        }
    } else {
        float bb[8];
#pragma unroll
        for (int j = 0; j < 8; ++j) bb[j] = bias1[ob + j] + bias2[ob + j];
#pragma unroll
        for (int i = 0; i < 4; ++i) {
            int n = n0 + tn4 + i;
            if (n >= NN) continue;
            size_t base = (size_t)n * HID + ob;
            float4 ox0 = *(const float4*)(outx + base);
            float4 ox1 = *(const float4*)(outx + base + 4);
            float4 ix0 = *(const float4*)(target + base);
            float4 ix1 = *(const float4*)(target + base + 4);
            float ox[8] = {ox0.x, ox0.y, ox0.z, ox0.w, ox1.x, ox1.y, ox1.z, ox1.w};
            float ix[8] = {ix0.x, ix0.y, ix0.z, ix0.w, ix1.x, ix1.y, ix1.z, ix1.w};
            float h[8];
#pragma unroll
            for (int j = 0; j < 8; ++j) {
                float t = acc[i][j] + bb[j];
                float z = 1.0f / (1.0f + expf(-t));
                h[j] = z * ox[j] + (1.0f - z) * ix[j];
            }
            float4 r0 = make_float4(h[0], h[1], h[2], h[3]);
            float4 r1 = make_float4(h[4], h[5], h[6], h[7]);
            *(float4*)(target + base) = r0;
            *(float4*)(target + base + 4) = r1;
        }
    }
}

// ---------------- pooling ----------------

__global__ void pool_kernel(const float* __restrict__ h, const int* __restrict__ batch,
                            float* __restrict__ pool) {
    int i = blockIdx.x * 256 + threadIdx.x;       // over NN*32 float4s
    if (i >= NN * 32) return;
    int n = i >> 5, c = (i & 31) << 2;
    int g = batch[n];
    float4 v = *(const float4*)(h + (size_t)i * 4);
    float* p = pool + (size_t)g * HID + c;
    atomicAdd(p + 0, v.x);
    atomicAdd(p + 1, v.y);
    atomicAdd(p + 2, v.z);
    atomicAdd(p + 3, v.w);
}

// ---------------- MLP head ----------------

__global__ void head_kernel(const float* __restrict__ pool1, const float* __restrict__ pool2,
                            const float* __restrict__ pool3, const float* __restrict__ cnt,
                            const float* __restrict__ eF,
                            const float* __restrict__ fc1W, const float* __restrict__ fc1b,
                            const float* __restrict__ fc3W, const float* __restrict__ fc3b,
                            float* __restrict__ out) {
    __shared__ float hg[3 * HID + EXD];
    __shared__ float hh[HID];
    int g = blockIdx.x, t = threadIdx.x;
    float ic = 1.0f / fmaxf(cnt[g], 1.0f);
    hg[t]           = pool1[(size_t)g * HID + t] * ic;
    hg[HID + t]     = pool2[(size_t)g * HID + t] * ic;
    hg[2 * HID + t] = pool3[(size_t)g * HID + t] * ic;
    if (t < EXD) hg[3 * HID + t] = eF[(size_t)g * EXD + t];
    __syncthreads();
    float acc = fc1b[t];
    for (int k = 0; k < 3 * HID + EXD; ++k) acc += hg[k] * fc1W[(size_t)k * HID + t];
    hh[t] = fmaxf(acc, 0.f);
    __syncthreads();
    if (t < OUTD) {
        float a2 = fc3b[t];
        for (int k = 0; k < HID; ++k) a2 += hh[k] * fc3W[(size_t)k * OUTD + t];
        out[(size_t)g * OUTD + t] = a2;
    }
}

// ---------------- launch ----------------

extern "C" void kernel_launch(void* const* d_in, const int* in_sizes, int n_in,
                              void* d_out, int out_size, void* d_ws, size_t ws_size,
                              hipStream_t stream) {
    const float* x      = (const float*)d_in[0];
    const float* eF     = (const float*)d_in[1];
    const int*   ei     = (const int*)d_in[2];
    const int*   batch  = (const int*)d_in[3];
    const int* src = ei;
    const int* dst = ei + NE;

    const float* W1 = (const float*)d_in[4];  const float* b1 = (const float*)d_in[5];
    const float* W2 = (const float*)d_in[6];  const float* b2 = (const float*)d_in[7];
    const float* W3 = (const float*)d_in[8];  const float* b3 = (const float*)d_in[9];
    const float* g1 = (const float*)d_in[10]; const float* be1 = (const float*)d_in[11];
    const float* g2 = (const float*)d_in[12]; const float* be2 = (const float*)d_in[13];
    const float* g3 = (const float*)d_in[14]; const float* be3 = (const float*)d_in[15];
    const float* s1_Wp = (const float*)d_in[16];
    const float* s1_Wi = (const float*)d_in[17]; const float* s1_bi = (const float*)d_in[18];
    const float* s1_Wo = (const float*)d_in[19]; const float* s1_bo = (const float*)d_in[20];
    const float* s2_Wi = (const float*)d_in[21]; const float* s2_bi = (const float*)d_in[22];
    const float* s2_Wo = (const float*)d_in[23]; const float* s2_bo = (const float*)d_in[24];
    const float* s3_Wi = (const float*)d_in[25]; const float* s3_bi = (const float*)d_in[26];
    const float* s3_Wo = (const float*)d_in[27]; const float* s3_bo = (const float*)d_in[28];
    const float* fc1W = (const float*)d_in[29]; const float* fc1b = (const float*)d_in[30];
    const float* fc3W = (const float*)d_in[31]; const float* fc3b = (const float*)d_in[32];

    float* ws = (float*)d_ws;
    size_t S = (size_t)NN * HID;                 // 12.8M floats
    float* xw   = ws;                            // also aliases deg (see below)
    float* agg  = ws + S;
    float* hbuf = ws + 2 * S;
    float* deg  = xw;                            // used only before xw is written
    float* dinv = ws + 3 * S;
    float* coef = dinv + NN;
    float* gsum = coef + NE;
    float* gsq  = gsum + HID;
    float* scl  = gsq + HID;
    float* shf  = scl + HID;
    float* pools = shf + HID;                    // 3 * NG * HID
    float* cnt   = pools + 3 * (size_t)NG * HID; // NG

    const int TB = 256;
    const int GB  = (NN + 63) / 64;              // gemm blocks
    const int EL  = (NN * 32 + TB - 1) / TB;     // elementwise float4 blocks
    const int EB  = (NE + TB - 1) / TB;
    const int NB  = (NN + TB - 1) / TB;
    const int SB  = (NE * 32 + TB - 1) / TB;     // scatter blocks

    // ---- one-time normalization / counts ----
    hipMemsetAsync(deg, 0, NN * sizeof(float), stream);
    hipMemsetAsync(pools, 0, (3 * (size_t)NG * HID + NG) * sizeof(float), stream);
    deg_kernel<<<EB, TB, 0, stream>>>(dst, deg);
    dinv_kernel<<<NB, TB, 0, stream>>>(deg, dinv);
    coef_kernel<<<EB, TB, 0, stream>>>(src, dst, dinv, coef);
    cnt_kernel<<<NB, TB, 0, stream>>>(batch, cnt);

    // ---- layer 1 ----
    gemm_kernel<<<GB, TB, 0, stream>>>(x, W1, IN_DIM, nullptr, nullptr, 0,
                                       nullptr, nullptr, nullptr, xw, 0);
    gemm_kernel<<<GB, TB, 0, stream>>>(x, s1_Wp, IN_DIM, nullptr, nullptr, 0,
                                       nullptr, nullptr, nullptr, hbuf, 0);   // in_x
    agg_init_kernel<<<EL, TB, 0, stream>>>(xw, dinv, b1, agg);
    scatter_kernel<<<SB, TB, 0, stream>>>(src, dst, coef, xw, agg);
    hipMemsetAsync(gsum, 0, 2 * HID * sizeof(float), stream);
    bn_stats_kernel<<<1024, TB, 0, stream>>>(agg, gsum, gsq);
    bn_finalize_kernel<<<1, HID, 0, stream>>>(gsum, gsq, g1, be1, scl, shf);
    bn_apply_relu_kernel<<<EL, TB, 0, stream>>>(agg, scl, shf);
    gemm_kernel<<<GB, TB, 0, stream>>>(agg, s1_Wo, HID, hbuf, s1_Wi, HID,
                                       s1_bo, s1_bi, agg, hbuf, 1);
    pool_kernel<<<EL, TB, 0, stream>>>(hbuf, batch, pools);

    // ---- layer 2 ----
    gemm_kernel<<<GB, TB, 0, stream>>>(hbuf, W2, HID, nullptr, nullptr, 0,
                                       nullptr, nullptr, nullptr, xw, 0);
    agg_init_kernel<<<EL, TB, 0, stream>>>(xw, dinv, b2, agg);
    scatter_kernel<<<SB, TB, 0, stream>>>(src, dst, coef, xw, agg);
    hipMemsetAsync(gsum, 0, 2 * HID * sizeof(float), stream);
    bn_stats_kernel<<<1024, TB, 0, stream>>>(agg, gsum, gsq);
    bn_finalize_kernel<<<1, HID, 0, stream>>>(gsum, gsq, g2, be2, scl, shf);
    bn_apply_relu_kernel<<<EL, TB, 0, stream>>>(agg, scl, shf);
    gemm_kernel<<<GB, TB, 0, stream>>>(agg, s2_Wo, HID, hbuf, s2_Wi, HID,
                                       s2_bo, s2_bi, agg, hbuf, 1);
    pool_kernel<<<EL, TB, 0, stream>>>(hbuf, batch, pools + (size_t)NG * HID);

    // ---- layer 3 ----
    gemm_kernel<<<GB, TB, 0, stream>>>(hbuf, W3, HID, nullptr, nullptr, 0,
                                       nullptr, nullptr, nullptr, xw, 0);
    agg_init_kernel<<<EL, TB, 0, stream>>>(xw, dinv, b3, agg);
    scatter_kernel<<<SB, TB, 0, stream>>>(src, dst, coef, xw, agg);
    hipMemsetAsync(gsum, 0, 2 * HID * sizeof(float), stream);
    bn_stats_kernel<<<1024, TB, 0, stream>>>(agg, gsum, gsq);
    bn_finalize_kernel<<<1, HID, 0, stream>>>(gsum, gsq, g3, be3, scl, shf);
    bn_apply_relu_kernel<<<EL, TB, 0, stream>>>(agg, scl, shf);
    gemm_kernel<<<GB, TB, 0, stream>>>(agg, s3_Wo, HID, hbuf, s3_Wi, HID,
                                       s3_bo, s3_bi, agg, hbuf, 1);
    pool_kernel<<<EL, TB, 0, stream>>>(hbuf, batch, pools + 2 * (size_t)NG * HID);

    // ---- head ----
    head_kernel<<<NG, HID, 0, stream>>>(pools, pools + (size_t)NG * HID,
                                        pools + 2 * (size_t)NG * HID, cnt, eF,
                                        fc1W, fc1b, fc3W, fc3b, (float*)d_out);
}

// Round 2
// 1482.145 us; speedup vs baseline: 6.5362x; 6.5362x over previous
//
#include <hip/hip_runtime.h>
#include <math.h>

#define NN 100000
#define NE 1600000
#define NG 1000
#define IN_DIM 64
#define HID 128
#define EXD 32
#define OUTD 10
#define BN_EPS 1e-5f

#define SCAN_B 256
#define NBLK ((NN + SCAN_B - 1) / SCAN_B)   // 391

// ---------------- degree / CSR build (layer-invariant) ----------------

__global__ void deg_kernel(const int* __restrict__ dst, int* __restrict__ deg) {
    int e = blockIdx.x * 256 + threadIdx.x;
    if (e < NE) atomicAdd(&deg[dst[e]], 1);
}

__global__ void dinv_kernel(const int* __restrict__ deg, float* __restrict__ dinv) {
    int i = blockIdx.x * 256 + threadIdx.x;
    if (i < NN) dinv[i] = rsqrtf((float)deg[i] + 1.0f);   // +1 self loop
}

// per-block exclusive scan of deg -> row_start; block totals -> bsums
__global__ void scan1_kernel(const int* __restrict__ deg, int* __restrict__ row_start,
                             int* __restrict__ bsums) {
    __shared__ int s[SCAN_B];
    int t = threadIdx.x;
    int i = blockIdx.x * SCAN_B + t;
    int v = (i < NN) ? deg[i] : 0;
    s[t] = v;
    __syncthreads();
    for (int off = 1; off < SCAN_B; off <<= 1) {
        int u = (t >= off) ? s[t - off] : 0;
        __syncthreads();
        s[t] += u;
        __syncthreads();
    }
    if (i < NN) row_start[i] = s[t] - v;      // exclusive within block
    if (t == SCAN_B - 1) bsums[blockIdx.x] = s[t];
}

// single-block exclusive scan of bsums (NBLK <= 512)
__global__ void scan2_kernel(int* __restrict__ bsums) {
    __shared__ int s[512];
    int t = threadIdx.x;
    int v = (t < NBLK) ? bsums[t] : 0;
    s[t] = v;
    __syncthreads();
    for (int off = 1; off < 512; off <<= 1) {
        int u = (t >= off) ? s[t - off] : 0;
        __syncthreads();
        s[t] += u;
        __syncthreads();
    }
    if (t < NBLK) bsums[t] = s[t] - v;        // exclusive
}

__global__ void scan3_kernel(int* __restrict__ row_start, const int* __restrict__ bsums) {
    int i = blockIdx.x * 256 + threadIdx.x;
    if (i < NN) row_start[i] += bsums[i >> 8];
    if (i == 0) row_start[NN] = NE;
}

// place each edge into its dst bucket; compute coef inline
__global__ void fill_kernel(const int* __restrict__ src, const int* __restrict__ dst,
                            const float* __restrict__ dinv, const int* __restrict__ row_start,
                            int* __restrict__ tmp, int* __restrict__ csr_src,
                            float* __restrict__ csr_cf) {
    int e = blockIdx.x * 256 + threadIdx.x;
    if (e >= NE) return;
    int d = dst[e], s = src[e];
    int p = atomicAdd(&tmp[d], 1);
    int idx = row_start[d] + p;
    csr_src[idx] = s;
    csr_cf[idx] = dinv[s] * dinv[d];
}

// graph start offsets from sorted batch
__global__ void gstart_kernel(const int* __restrict__ batch, int* __restrict__ gstart) {
    int n = blockIdx.x * 256 + threadIdx.x;
    if (n >= NN) return;
    int bc = batch[n];
    int bp = (n == 0) ? -1 : batch[n - 1];
    for (int g = bp + 1; g <= bc; ++g) gstart[g] = n;
    if (n == NN - 1)
        for (int g = bc + 1; g <= NG; ++g) gstart[g] = NN;
}

// ---------------- GCN aggregation: pull-gather, no atomics ----------------
// agg[n,:] = sum_{e in CSR[n]} xw[src_e,:]*cf_e + xw[n,:]*dinv[n]^2 + b
__launch_bounds__(256)
__global__ void gather_kernel(const int* __restrict__ row_start,
                              const int* __restrict__ csr_src,
                              const float* __restrict__ csr_cf,
                              const float* __restrict__ xw,
                              const float* __restrict__ dinv,
                              const float* __restrict__ b,
                              float* __restrict__ agg) {
    int node = blockIdx.x * 4 + (threadIdx.x >> 6);
    int lane = threadIdx.x & 63;
    if (node >= NN) return;
    int rs = row_start[node], re = row_start[node + 1];
    float d = dinv[node];
    float d2 = d * d;
    size_t fo = (size_t)lane * 2;
    float2 self = *(const float2*)(xw + (size_t)node * HID + fo);
    float2 acc;
    acc.x = self.x * d2 + b[fo];
    acc.y = self.y * d2 + b[fo + 1];
    int e = rs;
    for (; e + 1 < re; e += 2) {
        int s0 = csr_src[e], s1 = csr_src[e + 1];
        float c0 = csr_cf[e], c1 = csr_cf[e + 1];
        float2 v0 = *(const float2*)(xw + (size_t)s0 * HID + fo);
        float2 v1 = *(const float2*)(xw + (size_t)s1 * HID + fo);
        acc.x += c0 * v0.x + c1 * v1.x;
        acc.y += c0 * v0.y + c1 * v1.y;
    }
    if (e < re) {
        int s0 = csr_src[e];
        float c0 = csr_cf[e];
        float2 v0 = *(const float2*)(xw + (size_t)s0 * HID + fo);
        acc.x += c0 * v0.x;
        acc.y += c0 * v0.y;
    }
    *(float2*)(agg + (size_t)node * HID + fo) = acc;
}

// ---------------- BatchNorm ----------------

__global__ void bn_stats_kernel(const float* __restrict__ agg,
                                float* __restrict__ gsum, float* __restrict__ gsq) {
    __shared__ float ss[256], sq[256];
    int t = threadIdx.x;
    int f = t & 127;
    int sub = t >> 7;
    float s = 0.f, q = 0.f;
    for (int r = blockIdx.x * 2 + sub; r < NN; r += gridDim.x * 2) {
        float v = agg[(size_t)r * HID + f];
        s += v; q += v * v;
    }
    ss[t] = s; sq[t] = q;
    __syncthreads();
    if (t < 128) {
        atomicAdd(&gsum[f], ss[t] + ss[t + 128]);
        atomicAdd(&gsq[f],  sq[t] + sq[t + 128]);
    }
}

__global__ void bn_finalize_kernel(const float* __restrict__ gsum, const float* __restrict__ gsq,
                                   const float* __restrict__ g, const float* __restrict__ be,
                                   float* __restrict__ scale, float* __restrict__ shift) {
    int f = threadIdx.x;
    float mu = gsum[f] * (1.0f / NN);
    float var = gsq[f] * (1.0f / NN) - mu * mu;
    float sc = g[f] * rsqrtf(var + BN_EPS);
    scale[f] = sc;
    shift[f] = be[f] - mu * sc;
}

__global__ void bn_apply_relu_kernel(float* __restrict__ agg,
                                     const float* __restrict__ scale,
                                     const float* __restrict__ shift) {
    int i = blockIdx.x * 256 + threadIdx.x;       // over NN*32 float4s
    if (i >= NN * 32) return;
    int c = (i & 31) << 2;
    float4 v = *(const float4*)(agg + (size_t)i * 4);
    v.x = fmaxf(v.x * scale[c + 0] + shift[c + 0], 0.f);
    v.y = fmaxf(v.y * scale[c + 1] + shift[c + 1], 0.f);
    v.z = fmaxf(v.z * scale[c + 2] + shift[c + 2], 0.f);
    v.w = fmaxf(v.w * scale[c + 3] + shift[c + 3], 0.f);
    *(float4*)(agg + (size_t)i * 4) = v;
}

// ---------------- GEMM (f32, register-tiled 64 nodes x 128 outs) ----------------
__launch_bounds__(256)
__global__ void gemm_kernel(const float* __restrict__ A1, const float* __restrict__ Wa, int K1,
                            const float* A2, const float* __restrict__ Wb, int K2,
                            const float* __restrict__ bias1, const float* __restrict__ bias2,
                            const float* __restrict__ outx, float* target, int mode) {
    __shared__ float As[64][17];
    __shared__ float Ws[16][128];
    int tid = threadIdx.x;
    int n0 = blockIdx.x * 64;
    int to = tid & 15;
    int tn = tid >> 4;
    int ob = to << 3;
    int tn4 = tn << 2;

    float acc[4][8];
#pragma unroll
    for (int i = 0; i < 4; ++i)
#pragma unroll
        for (int j = 0; j < 8; ++j) acc[i][j] = 0.f;

    int r  = tid >> 2;
    int cc = (tid & 3) << 2;
    int kr = tid >> 4;
    int oo = (tid & 15) << 3;

    for (int pass = 0; pass < 2; ++pass) {
        const float* A = pass ? A2 : A1;
        const float* W = pass ? Wb : Wa;
        int K = pass ? K2 : K1;
        if (K == 0) break;
        for (int k0 = 0; k0 < K; k0 += 16) {
            int n = n0 + r;
            float4 av = make_float4(0.f, 0.f, 0.f, 0.f);
            if (n < NN) av = *(const float4*)(A + (size_t)n * K + k0 + cc);
            As[r][cc + 0] = av.x; As[r][cc + 1] = av.y;
            As[r][cc + 2] = av.z; As[r][cc + 3] = av.w;
            float4 w0 = *(const float4*)(W + (size_t)(k0 + kr) * HID + oo);
            float4 w1 = *(const float4*)(W + (size_t)(k0 + kr) * HID + oo + 4);
            *(float4*)&Ws[kr][oo]     = w0;
            *(float4*)&Ws[kr][oo + 4] = w1;
            __syncthreads();
#pragma unroll
            for (int k = 0; k < 16; ++k) {
                float a[4];
                a[0] = As[tn4 + 0][k]; a[1] = As[tn4 + 1][k];
                a[2] = As[tn4 + 2][k]; a[3] = As[tn4 + 3][k];
                float4 w0v = *(const float4*)&Ws[k][ob];
                float4 w1v = *(const float4*)&Ws[k][ob + 4];
                float w[8] = {w0v.x, w0v.y, w0v.z, w0v.w, w1v.x, w1v.y, w1v.z, w1v.w};
#pragma unroll
                for (int i = 0; i < 4; ++i)
#pragma unroll
                    for (int j = 0; j < 8; ++j) acc[i][j] += a[i] * w[j];
            }
            __syncthreads();
        }
    }

    if (mode == 0) {
#pragma unroll
        for (int i = 0; i < 4; ++i) {
            int n = n0 + tn4 + i;
            if (n >= NN) continue;
            float* p = target + (size_t)n * HID + ob;
            float4 r0 = make_float4(acc[i][0], acc[i][1], acc[i][2], acc[i][3]);
            float4 r1 = make_float4(acc[i][4], acc[i][5], acc[i][6], acc[i][7]);
            *(float4*)p = r0;
            *(float4*)(p + 4) = r1;
        }
    } else {
        float bb[8];
#pragma unroll
        for (int j = 0; j < 8; ++j) bb[j] = bias1[ob + j] + bias2[ob + j];
#pragma unroll
        for (int i = 0; i < 4; ++i) {
            int n = n0 + tn4 + i;
            if (n >= NN) continue;
            size_t base = (size_t)n * HID + ob;
            float4 ox0 = *(const float4*)(outx + base);
            float4 ox1 = *(const float4*)(outx + base + 4);
            float4 ix0 = *(const float4*)(target + base);
            float4 ix1 = *(const float4*)(target + base + 4);
            float ox[8] = {ox0.x, ox0.y, ox0.z, ox0.w, ox1.x, ox1.y, ox1.z, ox1.w};
            float ix[8] = {ix0.x, ix0.y, ix0.z, ix0.w, ix1.x, ix1.y, ix1.z, ix1.w};
            float h[8];
#pragma unroll
            for (int j = 0; j < 8; ++j) {
                float t = acc[i][j] + bb[j];
                float z = 1.0f / (1.0f + expf(-t));
                h[j] = z * ox[j] + (1.0f - z) * ix[j];
            }
            float4 r0 = make_float4(h[0], h[1], h[2], h[3]);
            float4 r1 = make_float4(h[4], h[5], h[6], h[7]);
            *(float4*)(target + base) = r0;
            *(float4*)(target + base + 4) = r1;
        }
    }
}

// ---------------- pooling (segment-based, no atomics, fused divide) ----------------

__global__ void pool_kernel(const float* __restrict__ h, const int* __restrict__ gstart,
                            float* __restrict__ pool) {
    int g = blockIdx.x, t = threadIdx.x;
    int s = gstart[g], e = gstart[g + 1];
    float acc = 0.f;
    for (int r = s; r < e; ++r) acc += h[(size_t)r * HID + t];
    pool[(size_t)g * HID + t] = acc / (float)max(e - s, 1);
}

// ---------------- MLP head ----------------

__global__ void head_kernel(const float* __restrict__ pool1, const float* __restrict__ pool2,
                            const float* __restrict__ pool3,
                            const float* __restrict__ eF,
                            const float* __restrict__ fc1W, const float* __restrict__ fc1b,
                            const float* __restrict__ fc3W, const float* __restrict__ fc3b,
                            float* __restrict__ out) {
    __shared__ float hg[3 * HID + EXD];
    __shared__ float hh[HID];
    int g = blockIdx.x, t = threadIdx.x;
    hg[t]           = pool1[(size_t)g * HID + t];
    hg[HID + t]     = pool2[(size_t)g * HID + t];
    hg[2 * HID + t] = pool3[(size_t)g * HID + t];
    if (t < EXD) hg[3 * HID + t] = eF[(size_t)g * EXD + t];
    __syncthreads();
    float acc = fc1b[t];
    for (int k = 0; k < 3 * HID + EXD; ++k) acc += hg[k] * fc1W[(size_t)k * HID + t];
    hh[t] = fmaxf(acc, 0.f);
    __syncthreads();
    if (t < OUTD) {
        float a2 = fc3b[t];
        for (int k = 0; k < HID; ++k) a2 += hh[k] * fc3W[(size_t)k * OUTD + t];
        out[(size_t)g * OUTD + t] = a2;
    }
}

// ---------------- launch ----------------

extern "C" void kernel_launch(void* const* d_in, const int* in_sizes, int n_in,
                              void* d_out, int out_size, void* d_ws, size_t ws_size,
                              hipStream_t stream) {
    const float* x      = (const float*)d_in[0];
    const float* eF     = (const float*)d_in[1];
    const int*   ei     = (const int*)d_in[2];
    const int*   batch  = (const int*)d_in[3];
    const int* src = ei;
    const int* dst = ei + NE;

    const float* W1 = (const float*)d_in[4];  const float* b1 = (const float*)d_in[5];
    const float* W2 = (const float*)d_in[6];  const float* b2 = (const float*)d_in[7];
    const float* W3 = (const float*)d_in[8];  const float* b3 = (const float*)d_in[9];
    const float* g1 = (const float*)d_in[10]; const float* be1 = (const float*)d_in[11];
    const float* g2 = (const float*)d_in[12]; const float* be2 = (const float*)d_in[13];
    const float* g3 = (const float*)d_in[14]; const float* be3 = (const float*)d_in[15];
    const float* s1_Wp = (const float*)d_in[16];
    const float* s1_Wi = (const float*)d_in[17]; const float* s1_bi = (const float*)d_in[18];
    const float* s1_Wo = (const float*)d_in[19]; const float* s1_bo = (const float*)d_in[20];
    const float* s2_Wi = (const float*)d_in[21]; const float* s2_bi = (const float*)d_in[22];
    const float* s2_Wo = (const float*)d_in[23]; const float* s2_bo = (const float*)d_in[24];
    const float* s3_Wi = (const float*)d_in[25]; const float* s3_bi = (const float*)d_in[26];
    const float* s3_Wo = (const float*)d_in[27]; const float* s3_bo = (const float*)d_in[28];
    const float* fc1W = (const float*)d_in[29]; const float* fc1b = (const float*)d_in[30];
    const float* fc3W = (const float*)d_in[31]; const float* fc3b = (const float*)d_in[32];

    float* ws = (float*)d_ws;
    size_t S = (size_t)NN * HID;                 // 12.8M floats
    float* xw   = ws;
    float* agg  = ws + S;
    float* hbuf = ws + 2 * S;
    // transient buffers aliased into the xw region (dead before first gemm)
    int*   deg  = (int*)xw;                      // NN
    int*   tmp  = (int*)xw + NN;                 // NN
    int*   bsums = (int*)xw + 2 * NN;            // NBLK
    // persistent
    float* dinv = ws + 3 * S;                    // NN
    int*   row_start = (int*)(dinv + NN);        // NN+1
    int*   csr_src   = row_start + NN + 1;       // NE
    float* csr_cf    = (float*)(csr_src + NE);   // NE
    int*   gstart    = (int*)(csr_cf + NE);      // NG+1
    float* gsum = (float*)(gstart + NG + 1);
    float* gsq  = gsum + HID;
    float* scl  = gsq + HID;
    float* shf  = scl + HID;
    float* pools = shf + HID;                    // 3 * NG * HID

    const int TB = 256;
    const int GB  = (NN + 63) / 64;              // gemm blocks
    const int EL  = (NN * 32 + TB - 1) / TB;     // elementwise float4 blocks
    const int EB  = (NE + TB - 1) / TB;
    const int NB  = (NN + TB - 1) / TB;
    const int AGB = (NN + 3) / 4;                // gather blocks (4 nodes/block)

    // ---- CSR build + graph offsets (before xw region is reused by gemm) ----
    hipMemsetAsync(deg, 0, 2 * NN * sizeof(int), stream);   // deg + tmp
    deg_kernel<<<EB, TB, 0, stream>>>(dst, deg);
    dinv_kernel<<<NB, TB, 0, stream>>>(deg, dinv);
    scan1_kernel<<<NBLK, SCAN_B, 0, stream>>>(deg, row_start, bsums);
    scan2_kernel<<<1, 512, 0, stream>>>(bsums);
    scan3_kernel<<<NB, TB, 0, stream>>>(row_start, bsums);
    fill_kernel<<<EB, TB, 0, stream>>>(src, dst, dinv, row_start, tmp, csr_src, csr_cf);
    gstart_kernel<<<NB, TB, 0, stream>>>(batch, gstart);

    // ---- layer 1 ----
    gemm_kernel<<<GB, TB, 0, stream>>>(x, W1, IN_DIM, nullptr, nullptr, 0,
                                       nullptr, nullptr, nullptr, xw, 0);
    gemm_kernel<<<GB, TB, 0, stream>>>(x, s1_Wp, IN_DIM, nullptr, nullptr, 0,
                                       nullptr, nullptr, nullptr, hbuf, 0);   // in_x
    gather_kernel<<<AGB, TB, 0, stream>>>(row_start, csr_src, csr_cf, xw, dinv, b1, agg);
    hipMemsetAsync(gsum, 0, 2 * HID * sizeof(float), stream);
    bn_stats_kernel<<<1024, TB, 0, stream>>>(agg, gsum, gsq);
    bn_finalize_kernel<<<1, HID, 0, stream>>>(gsum, gsq, g1, be1, scl, shf);
    bn_apply_relu_kernel<<<EL, TB, 0, stream>>>(agg, scl, shf);
    gemm_kernel<<<GB, TB, 0, stream>>>(agg, s1_Wo, HID, hbuf, s1_Wi, HID,
                                       s1_bo, s1_bi, agg, hbuf, 1);
    pool_kernel<<<NG, HID, 0, stream>>>(hbuf, gstart, pools);

    // ---- layer 2 ----
    gemm_kernel<<<GB, TB, 0, stream>>>(hbuf, W2, HID, nullptr, nullptr, 0,
                                       nullptr, nullptr, nullptr, xw, 0);
    gather_kernel<<<AGB, TB, 0, stream>>>(row_start, csr_src, csr_cf, xw, dinv, b2, agg);
    hipMemsetAsync(gsum, 0, 2 * HID * sizeof(float), stream);
    bn_stats_kernel<<<1024, TB, 0, stream>>>(agg, gsum, gsq);
    bn_finalize_kernel<<<1, HID, 0, stream>>>(gsum, gsq, g2, be2, scl, shf);
    bn_apply_relu_kernel<<<EL, TB, 0, stream>>>(agg, scl, shf);
    gemm_kernel<<<GB, TB, 0, stream>>>(agg, s2_Wo, HID, hbuf, s2_Wi, HID,
                                       s2_bo, s2_bi, agg, hbuf, 1);
    pool_kernel<<<NG, HID, 0, stream>>>(hbuf, gstart, pools + (size_t)NG * HID);

    // ---- layer 3 ----
    gemm_kernel<<<GB, TB, 0, stream>>>(hbuf, W3, HID, nullptr, nullptr, 0,
                                       nullptr, nullptr, nullptr, xw, 0);
    gather_kernel<<<AGB, TB, 0, stream>>>(row_start, csr_src, csr_cf, xw, dinv, b3, agg);
    hipMemsetAsync(gsum, 0, 2 * HID * sizeof(float), stream);
    bn_stats_kernel<<<1024, TB, 0, stream>>>(agg, gsum, gsq);
    bn_finalize_kernel<<<1, HID, 0, stream>>>(gsum, gsq, g3, be3, scl, shf);
    bn_apply_relu_kernel<<<EL, TB, 0, stream>>>(agg, scl, shf);
    gemm_kernel<<<GB, TB, 0, stream>>>(agg, s3_Wo, HID, hbuf, s3_Wi, HID,
                                       s3_bo, s3_bi, agg, hbuf, 1);
    pool_kernel<<<NG, HID, 0, stream>>>(hbuf, gstart, pools + 2 * (size_t)NG * HID);

    // ---- head ----
    head_kernel<<<NG, HID, 0, stream>>>(pools, pools + (size_t)NG * HID,
                                        pools + 2 * (size_t)NG * HID, eF,
                                        fc1W, fc1b, fc3W, fc3b, (float*)d_out);
}

// Round 3
// 1265.844 us; speedup vs baseline: 7.6531x; 1.1709x over previous
//
#include <hip/hip_runtime.h>
#include <math.h>

#define NN 100000
#define NE 1600000
#define NG 1000
#define IN_DIM 64
#define HID 128
#define EXD 32
#define OUTD 10
#define BN_EPS 1e-5f

#define SCAN_B 256
#define NBLK ((NN + SCAN_B - 1) / SCAN_B)   // 391

__device__ __forceinline__ float bf2f(unsigned short h) {
    return __uint_as_float((unsigned int)h << 16);
}
__device__ __forceinline__ unsigned short f2bf(float f) {
    unsigned int u = __float_as_uint(f);
    u += 0x7fffu + ((u >> 16) & 1u);        // round to nearest even
    return (unsigned short)(u >> 16);
}

// ---------------- degree / CSR build (layer-invariant) ----------------

__global__ void deg_kernel(const int* __restrict__ dst, int* __restrict__ deg) {
    int e = blockIdx.x * 256 + threadIdx.x;
    if (e < NE) atomicAdd(&deg[dst[e]], 1);
}

__global__ void dinv_kernel(const int* __restrict__ deg, float* __restrict__ dinv) {
    int i = blockIdx.x * 256 + threadIdx.x;
    if (i < NN) dinv[i] = rsqrtf((float)deg[i] + 1.0f);   // +1 self loop
}

__global__ void scan1_kernel(const int* __restrict__ deg, int* __restrict__ row_start,
                             int* __restrict__ bsums) {
    __shared__ int s[SCAN_B];
    int t = threadIdx.x;
    int i = blockIdx.x * SCAN_B + t;
    int v = (i < NN) ? deg[i] : 0;
    s[t] = v;
    __syncthreads();
    for (int off = 1; off < SCAN_B; off <<= 1) {
        int u = (t >= off) ? s[t - off] : 0;
        __syncthreads();
        s[t] += u;
        __syncthreads();
    }
    if (i < NN) row_start[i] = s[t] - v;
    if (t == SCAN_B - 1) bsums[blockIdx.x] = s[t];
}

__global__ void scan2_kernel(int* __restrict__ bsums) {
    __shared__ int s[512];
    int t = threadIdx.x;
    int v = (t < NBLK) ? bsums[t] : 0;
    s[t] = v;
    __syncthreads();
    for (int off = 1; off < 512; off <<= 1) {
        int u = (t >= off) ? s[t - off] : 0;
        __syncthreads();
        s[t] += u;
        __syncthreads();
    }
    if (t < NBLK) bsums[t] = s[t] - v;
}

__global__ void scan3_kernel(int* __restrict__ row_start, const int* __restrict__ bsums) {
    int i = blockIdx.x * 256 + threadIdx.x;
    if (i < NN) row_start[i] += bsums[i >> 8];
    if (i == 0) row_start[NN] = NE;
}

__global__ void fill_kernel(const int* __restrict__ src, const int* __restrict__ dst,
                            const float* __restrict__ dinv, const int* __restrict__ row_start,
                            int* __restrict__ tmp, int* __restrict__ csr_src,
                            float* __restrict__ csr_cf) {
    int e = blockIdx.x * 256 + threadIdx.x;
    if (e >= NE) return;
    int d = dst[e], s = src[e];
    int p = atomicAdd(&tmp[d], 1);
    int idx = row_start[d] + p;
    csr_src[idx] = s;
    csr_cf[idx] = dinv[s] * dinv[d];
}

__global__ void gstart_kernel(const int* __restrict__ batch, int* __restrict__ gstart) {
    int n = blockIdx.x * 256 + threadIdx.x;
    if (n >= NN) return;
    int bc = batch[n];
    int bp = (n == 0) ? -1 : batch[n - 1];
    for (int g = bp + 1; g <= bc; ++g) gstart[g] = n;
    if (n == NN - 1)
        for (int g = bc + 1; g <= NG; ++g) gstart[g] = NN;
}

// ---------------- GCN aggregation: pull-gather on bf16 rows ----------------
// 8 nodes per block, 32 lanes per node, lane covers feats [4*lane .. 4*lane+3]
__launch_bounds__(256)
__global__ void gather_kernel(const int* __restrict__ row_start,
                              const int* __restrict__ csr_src,
                              const float* __restrict__ csr_cf,
                              const unsigned short* __restrict__ xwb,
                              const float* __restrict__ dinv,
                              const float* __restrict__ b,
                              float* __restrict__ agg) {
    int node = blockIdx.x * 8 + (threadIdx.x >> 5);
    int lane = threadIdx.x & 31;
    if (node >= NN) return;
    int rs = row_start[node], re = row_start[node + 1];
    float d = dinv[node];
    float d2 = d * d;
    int fo = lane << 2;
    ushort4 sv = *(const ushort4*)(xwb + (size_t)node * HID + fo);
    float4 acc;
    acc.x = bf2f(sv.x) * d2 + b[fo + 0];
    acc.y = bf2f(sv.y) * d2 + b[fo + 1];
    acc.z = bf2f(sv.z) * d2 + b[fo + 2];
    acc.w = bf2f(sv.w) * d2 + b[fo + 3];
    int e = rs;
    for (; e + 1 < re; e += 2) {
        int s0 = csr_src[e], s1 = csr_src[e + 1];
        float c0 = csr_cf[e], c1 = csr_cf[e + 1];
        ushort4 r0 = *(const ushort4*)(xwb + (size_t)s0 * HID + fo);
        ushort4 r1 = *(const ushort4*)(xwb + (size_t)s1 * HID + fo);
        acc.x += c0 * bf2f(r0.x) + c1 * bf2f(r1.x);
        acc.y += c0 * bf2f(r0.y) + c1 * bf2f(r1.y);
        acc.z += c0 * bf2f(r0.z) + c1 * bf2f(r1.z);
        acc.w += c0 * bf2f(r0.w) + c1 * bf2f(r1.w);
    }
    if (e < re) {
        int s0 = csr_src[e];
        float c0 = csr_cf[e];
        ushort4 r0 = *(const ushort4*)(xwb + (size_t)s0 * HID + fo);
        acc.x += c0 * bf2f(r0.x);
        acc.y += c0 * bf2f(r0.y);
        acc.z += c0 * bf2f(r0.z);
        acc.w += c0 * bf2f(r0.w);
    }
    *(float4*)(agg + (size_t)node * HID + fo) = acc;
}

// ---------------- BatchNorm ----------------

__global__ void bn_stats_kernel(const float* __restrict__ agg,
                                float* __restrict__ gsum, float* __restrict__ gsq) {
    __shared__ float ss[256], sq[256];
    int t = threadIdx.x;
    int f = t & 127;
    int sub = t >> 7;
    float s = 0.f, q = 0.f;
    for (int r = blockIdx.x * 2 + sub; r < NN; r += gridDim.x * 2) {
        float v = agg[(size_t)r * HID + f];
        s += v; q += v * v;
    }
    ss[t] = s; sq[t] = q;
    __syncthreads();
    if (t < 128) {
        atomicAdd(&gsum[f], ss[t] + ss[t + 128]);
        atomicAdd(&gsq[f],  sq[t] + sq[t + 128]);
    }
}

__global__ void bn_finalize_kernel(const float* __restrict__ gsum, const float* __restrict__ gsq,
                                   const float* __restrict__ g, const float* __restrict__ be,
                                   float* __restrict__ scale, float* __restrict__ shift) {
    int f = threadIdx.x;
    float mu = gsum[f] * (1.0f / NN);
    float var = gsq[f] * (1.0f / NN) - mu * mu;
    float sc = g[f] * rsqrtf(var + BN_EPS);
    scale[f] = sc;
    shift[f] = be[f] - mu * sc;
}

__global__ void bn_apply_relu_kernel(float* __restrict__ agg,
                                     const float* __restrict__ scale,
                                     const float* __restrict__ shift) {
    int i = blockIdx.x * 256 + threadIdx.x;
    if (i >= NN * 32) return;
    int c = (i & 31) << 2;
    float4 v = *(const float4*)(agg + (size_t)i * 4);
    v.x = fmaxf(v.x * scale[c + 0] + shift[c + 0], 0.f);
    v.y = fmaxf(v.y * scale[c + 1] + shift[c + 1], 0.f);
    v.z = fmaxf(v.z * scale[c + 2] + shift[c + 2], 0.f);
    v.w = fmaxf(v.w * scale[c + 3] + shift[c + 3], 0.f);
    *(float4*)(agg + (size_t)i * 4) = v;
}

// ---------------- GEMM (f32, 64 nodes x 128 outs, k-major A tile) ----------------
// mode 0: targetf = A1 @ Wa
// mode 1: t = A1@Wa + b1 + A2@Wb + b2; z=sigmoid(t); targetf = z*outx+(1-z)*targetf
// mode 2: targetb = bf16(A1 @ Wa)
__launch_bounds__(256)
__global__ void gemm_kernel(const float* __restrict__ A1, const float* __restrict__ Wa, int K1,
                            const float* A2, const float* __restrict__ Wb, int K2,
                            const float* __restrict__ bias1, const float* __restrict__ bias2,
                            const float* __restrict__ outx, float* targetf,
                            unsigned short* targetb, int mode) {
    __shared__ float As[16][72];        // k-major: As[k][node], pad->float4-aligned rows
    __shared__ float Ws[16][128];
    int tid = threadIdx.x;
    int n0 = blockIdx.x * 64;
    int to = tid & 15;
    int tn = tid >> 4;
    int ob = to << 3;
    int tn4 = tn << 2;

    float acc[4][8];
#pragma unroll
    for (int i = 0; i < 4; ++i)
#pragma unroll
        for (int j = 0; j < 8; ++j) acc[i][j] = 0.f;

    int r  = tid >> 2;          // node 0..63 for A staging
    int cc = (tid & 3) << 2;    // k offset 0,4,8,12
    int kr = tid >> 4;          // W staging k row 0..15
    int oo = (tid & 15) << 3;   // W staging col

    for (int pass = 0; pass < 2; ++pass) {
        const float* A = pass ? A2 : A1;
        const float* W = pass ? Wb : Wa;
        int K = pass ? K2 : K1;
        if (K == 0) break;
        for (int k0 = 0; k0 < K; k0 += 16) {
            int n = n0 + r;
            float4 av = make_float4(0.f, 0.f, 0.f, 0.f);
            if (n < NN) av = *(const float4*)(A + (size_t)n * K + k0 + cc);
            As[cc + 0][r] = av.x; As[cc + 1][r] = av.y;
            As[cc + 2][r] = av.z; As[cc + 3][r] = av.w;
            float4 w0 = *(const float4*)(W + (size_t)(k0 + kr) * HID + oo);
            float4 w1 = *(const float4*)(W + (size_t)(k0 + kr) * HID + oo + 4);
            *(float4*)&Ws[kr][oo]     = w0;
            *(float4*)&Ws[kr][oo + 4] = w1;
            __syncthreads();
#pragma unroll
            for (int k = 0; k < 16; ++k) {
                float4 a4 = *(const float4*)&As[k][tn4];
                float a[4] = {a4.x, a4.y, a4.z, a4.w};
                float4 w0v = *(const float4*)&Ws[k][ob];
                float4 w1v = *(const float4*)&Ws[k][ob + 4];
                float w[8] = {w0v.x, w0v.y, w0v.z, w0v.w, w1v.x, w1v.y, w1v.z, w1v.w};
#pragma unroll
                for (int i = 0; i < 4; ++i)
#pragma unroll
                    for (int j = 0; j < 8; ++j) acc[i][j] += a[i] * w[j];
            }
            __syncthreads();
        }
    }

    if (mode == 0) {
#pragma unroll
        for (int i = 0; i < 4; ++i) {
            int n = n0 + tn4 + i;
            if (n >= NN) continue;
            float* p = targetf + (size_t)n * HID + ob;
            *(float4*)p       = make_float4(acc[i][0], acc[i][1], acc[i][2], acc[i][3]);
            *(float4*)(p + 4) = make_float4(acc[i][4], acc[i][5], acc[i][6], acc[i][7]);
        }
    } else if (mode == 2) {
#pragma unroll
        for (int i = 0; i < 4; ++i) {
            int n = n0 + tn4 + i;
            if (n >= NN) continue;
            unsigned int pk[4];
#pragma unroll
            for (int j = 0; j < 4; ++j)
                pk[j] = (unsigned int)f2bf(acc[i][2 * j]) |
                        ((unsigned int)f2bf(acc[i][2 * j + 1]) << 16);
            *(uint4*)(targetb + (size_t)n * HID + ob) = make_uint4(pk[0], pk[1], pk[2], pk[3]);
        }
    } else {
        float bb[8];
#pragma unroll
        for (int j = 0; j < 8; ++j) bb[j] = bias1[ob + j] + bias2[ob + j];
#pragma unroll
        for (int i = 0; i < 4; ++i) {
            int n = n0 + tn4 + i;
            if (n >= NN) continue;
            size_t base = (size_t)n * HID + ob;
            float4 ox0 = *(const float4*)(outx + base);
            float4 ox1 = *(const float4*)(outx + base + 4);
            float4 ix0 = *(const float4*)(targetf + base);
            float4 ix1 = *(const float4*)(targetf + base + 4);
            float ox[8] = {ox0.x, ox0.y, ox0.z, ox0.w, ox1.x, ox1.y, ox1.z, ox1.w};
            float ix[8] = {ix0.x, ix0.y, ix0.z, ix0.w, ix1.x, ix1.y, ix1.z, ix1.w};
            float h[8];
#pragma unroll
            for (int j = 0; j < 8; ++j) {
                float t = acc[i][j] + bb[j];
                float z = 1.0f / (1.0f + expf(-t));
                h[j] = z * ox[j] + (1.0f - z) * ix[j];
            }
            *(float4*)(targetf + base)     = make_float4(h[0], h[1], h[2], h[3]);
            *(float4*)(targetf + base + 4) = make_float4(h[4], h[5], h[6], h[7]);
        }
    }
}

// ---------------- pooling (segment-based, vectorized) ----------------

__global__ void pool_kernel(const float* __restrict__ h, const int* __restrict__ gstart,
                            float* __restrict__ pool) {
    __shared__ float red[8][128];
    int g = blockIdx.x, t = threadIdx.x;
    int lane = t & 31, sub = t >> 5;
    int s = gstart[g], e = gstart[g + 1];
    float4 acc = make_float4(0.f, 0.f, 0.f, 0.f);
    for (int r = s + sub; r < e; r += 8) {
        float4 v = *(const float4*)(h + (size_t)r * HID + (lane << 2));
        acc.x += v.x; acc.y += v.y; acc.z += v.z; acc.w += v.w;
    }
    *(float4*)&red[sub][lane << 2] = acc;
    __syncthreads();
    if (t < 128) {
        float a = 0.f;
#pragma unroll
        for (int i = 0; i < 8; ++i) a += red[i][t];
        pool[(size_t)g * HID + t] = a / (float)max(e - s, 1);
    }
}

// ---------------- MLP head ----------------

__global__ void head_kernel(const float* __restrict__ pool1, const float* __restrict__ pool2,
                            const float* __restrict__ pool3,
                            const float* __restrict__ eF,
                            const float* __restrict__ fc1W, const float* __restrict__ fc1b,
                            const float* __restrict__ fc3W, const float* __restrict__ fc3b,
                            float* __restrict__ out) {
    __shared__ float hg[3 * HID + EXD];
    __shared__ float hh[HID];
    int g = blockIdx.x, t = threadIdx.x;
    hg[t]           = pool1[(size_t)g * HID + t];
    hg[HID + t]     = pool2[(size_t)g * HID + t];
    hg[2 * HID + t] = pool3[(size_t)g * HID + t];
    if (t < EXD) hg[3 * HID + t] = eF[(size_t)g * EXD + t];
    __syncthreads();
    float acc = fc1b[t];
    for (int k = 0; k < 3 * HID + EXD; ++k) acc += hg[k] * fc1W[(size_t)k * HID + t];
    hh[t] = fmaxf(acc, 0.f);
    __syncthreads();
    if (t < OUTD) {
        float a2 = fc3b[t];
        for (int k = 0; k < HID; ++k) a2 += hh[k] * fc3W[(size_t)k * OUTD + t];
        out[(size_t)g * OUTD + t] = a2;
    }
}

// ---------------- launch ----------------

extern "C" void kernel_launch(void* const* d_in, const int* in_sizes, int n_in,
                              void* d_out, int out_size, void* d_ws, size_t ws_size,
                              hipStream_t stream) {
    const float* x      = (const float*)d_in[0];
    const float* eF     = (const float*)d_in[1];
    const int*   ei     = (const int*)d_in[2];
    const int*   batch  = (const int*)d_in[3];
    const int* src = ei;
    const int* dst = ei + NE;

    const float* W1 = (const float*)d_in[4];  const float* b1 = (const float*)d_in[5];
    const float* W2 = (const float*)d_in[6];  const float* b2 = (const float*)d_in[7];
    const float* W3 = (const float*)d_in[8];  const float* b3 = (const float*)d_in[9];
    const float* g1 = (const float*)d_in[10]; const float* be1 = (const float*)d_in[11];
    const float* g2 = (const float*)d_in[12]; const float* be2 = (const float*)d_in[13];
    const float* g3 = (const float*)d_in[14]; const float* be3 = (const float*)d_in[15];
    const float* s1_Wp = (const float*)d_in[16];
    const float* s1_Wi = (const float*)d_in[17]; const float* s1_bi = (const float*)d_in[18];
    const float* s1_Wo = (const float*)d_in[19]; const float* s1_bo = (const float*)d_in[20];
    const float* s2_Wi = (const float*)d_in[21]; const float* s2_bi = (const float*)d_in[22];
    const float* s2_Wo = (const float*)d_in[23]; const float* s2_bo = (const float*)d_in[24];
    const float* s3_Wi = (const float*)d_in[25]; const float* s3_bi = (const float*)d_in[26];
    const float* s3_Wo = (const float*)d_in[27]; const float* s3_bo = (const float*)d_in[28];
    const float* fc1W = (const float*)d_in[29]; const float* fc1b = (const float*)d_in[30];
    const float* fc3W = (const float*)d_in[31]; const float* fc3b = (const float*)d_in[32];

    float* ws = (float*)d_ws;
    size_t S = (size_t)NN * HID;                 // 12.8M floats
    unsigned short* xwb = (unsigned short*)ws;   // NN*HID bf16 (25.6 MB in 51.2 MB slot)
    float* agg  = ws + S;
    float* hbuf = ws + 2 * S;
    // transient buffers aliased into the xwb region (dead before first gemm)
    int*   deg  = (int*)ws;                      // NN
    int*   tmp  = (int*)ws + NN;                 // NN
    int*   bsums = (int*)ws + 2 * NN;            // NBLK
    // persistent
    float* dinv = ws + 3 * S;                    // NN
    int*   row_start = (int*)(dinv + NN);        // NN+1
    int*   csr_src   = row_start + NN + 1;       // NE
    float* csr_cf    = (float*)(csr_src + NE);   // NE
    int*   gstart    = (int*)(csr_cf + NE);      // NG+1
    float* gsum = (float*)(gstart + NG + 1);
    float* gsq  = gsum + HID;
    float* scl  = gsq + HID;
    float* shf  = scl + HID;
    float* pools = shf + HID;                    // 3 * NG * HID

    const int TB = 256;
    const int GB  = (NN + 63) / 64;
    const int EL  = (NN * 32 + TB - 1) / TB;
    const int EB  = (NE + TB - 1) / TB;
    const int NB  = (NN + TB - 1) / TB;
    const int AGB = (NN + 7) / 8;                // gather blocks (8 nodes/block)

    // ---- CSR build + graph offsets ----
    hipMemsetAsync(deg, 0, 2 * NN * sizeof(int), stream);
    deg_kernel<<<EB, TB, 0, stream>>>(dst, deg);
    dinv_kernel<<<NB, TB, 0, stream>>>(deg, dinv);
    scan1_kernel<<<NBLK, SCAN_B, 0, stream>>>(deg, row_start, bsums);
    scan2_kernel<<<1, 512, 0, stream>>>(bsums);
    scan3_kernel<<<NB, TB, 0, stream>>>(row_start, bsums);
    fill_kernel<<<EB, TB, 0, stream>>>(src, dst, dinv, row_start, tmp, csr_src, csr_cf);
    gstart_kernel<<<NB, TB, 0, stream>>>(batch, gstart);

    // ---- layer 1 ----
    gemm_kernel<<<GB, TB, 0, stream>>>(x, W1, IN_DIM, nullptr, nullptr, 0,
                                       nullptr, nullptr, nullptr, nullptr, xwb, 2);
    gemm_kernel<<<GB, TB, 0, stream>>>(x, s1_Wp, IN_DIM, nullptr, nullptr, 0,
                                       nullptr, nullptr, nullptr, hbuf, nullptr, 0);
    gather_kernel<<<AGB, TB, 0, stream>>>(row_start, csr_src, csr_cf, xwb, dinv, b1, agg);
    hipMemsetAsync(gsum, 0, 2 * HID * sizeof(float), stream);
    bn_stats_kernel<<<1024, TB, 0, stream>>>(agg, gsum, gsq);
    bn_finalize_kernel<<<1, HID, 0, stream>>>(gsum, gsq, g1, be1, scl, shf);
    bn_apply_relu_kernel<<<EL, TB, 0, stream>>>(agg, scl, shf);
    gemm_kernel<<<GB, TB, 0, stream>>>(agg, s1_Wo, HID, hbuf, s1_Wi, HID,
                                       s1_bo, s1_bi, agg, hbuf, nullptr, 1);
    pool_kernel<<<NG, TB, 0, stream>>>(hbuf, gstart, pools);

    // ---- layer 2 ----
    gemm_kernel<<<GB, TB, 0, stream>>>(hbuf, W2, HID, nullptr, nullptr, 0,
                                       nullptr, nullptr, nullptr, nullptr, xwb, 2);
    gather_kernel<<<AGB, TB, 0, stream>>>(row_start, csr_src, csr_cf, xwb, dinv, b2, agg);
    hipMemsetAsync(gsum, 0, 2 * HID * sizeof(float), stream);
    bn_stats_kernel<<<1024, TB, 0, stream>>>(agg, gsum, gsq);
    bn_finalize_kernel<<<1, HID, 0, stream>>>(gsum, gsq, g2, be2, scl, shf);
    bn_apply_relu_kernel<<<EL, TB, 0, stream>>>(agg, scl, shf);
    gemm_kernel<<<GB, TB, 0, stream>>>(agg, s2_Wo, HID, hbuf, s2_Wi, HID,
                                       s2_bo, s2_bi, agg, hbuf, nullptr, 1);
    pool_kernel<<<NG, TB, 0, stream>>>(hbuf, gstart, pools + (size_t)NG * HID);

    // ---- layer 3 ----
    gemm_kernel<<<GB, TB, 0, stream>>>(hbuf, W3, HID, nullptr, nullptr, 0,
                                       nullptr, nullptr, nullptr, nullptr, xwb, 2);
    gather_kernel<<<AGB, TB, 0, stream>>>(row_start, csr_src, csr_cf, xwb, dinv, b3, agg);
    hipMemsetAsync(gsum, 0, 2 * HID * sizeof(float), stream);
    bn_stats_kernel<<<1024, TB, 0, stream>>>(agg, gsum, gsq);
    bn_finalize_kernel<<<1, HID, 0, stream>>>(gsum, gsq, g3, be3, scl, shf);
    bn_apply_relu_kernel<<<EL, TB, 0, stream>>>(agg, scl, shf);
    gemm_kernel<<<GB, TB, 0, stream>>>(agg, s3_Wo, HID, hbuf, s3_Wi, HID,
                                       s3_bo, s3_bi, agg, hbuf, nullptr, 1);
    pool_kernel<<<NG, TB, 0, stream>>>(hbuf, gstart, pools + 2 * (size_t)NG * HID);

    // ---- head ----
    head_kernel<<<NG, HID, 0, stream>>>(pools, pools + (size_t)NG * HID,
                                        pools + 2 * (size_t)NG * HID, eF,
                                        fc1W, fc1b, fc3W, fc3b, (float*)d_out);
}

// Round 4
// 1002.775 us; speedup vs baseline: 9.6608x; 1.2623x over previous
//
#include <hip/hip_runtime.h>
#include <math.h>

#define NN 100000
#define NE 1600000
#define NG 1000
#define IN_DIM 64
#define HID 128
#define EXD 32
#define OUTD 10
#define BN_EPS 1e-5f

#define SCAN_B 256
#define NBLK ((NN + SCAN_B - 1) / SCAN_B)   // 391

typedef __attribute__((ext_vector_type(8))) short bf16x8;
typedef __attribute__((ext_vector_type(4))) float f32x4;

__device__ __forceinline__ float bf2f(unsigned short h) {
    return __uint_as_float((unsigned int)h << 16);
}
__device__ __forceinline__ unsigned short f2bf(float f) {
    unsigned int u = __float_as_uint(f);
    u += 0x7fffu + ((u >> 16) & 1u);        // round to nearest even
    return (unsigned short)(u >> 16);
}

// ---------------- degree / CSR build (layer-invariant) ----------------

__global__ void deg_kernel(const int* __restrict__ dst, int* __restrict__ deg) {
    int e = blockIdx.x * 256 + threadIdx.x;
    if (e < NE) atomicAdd(&deg[dst[e]], 1);
}

__global__ void dinv_kernel(const int* __restrict__ deg, float* __restrict__ dinv) {
    int i = blockIdx.x * 256 + threadIdx.x;
    if (i < NN) dinv[i] = rsqrtf((float)deg[i] + 1.0f);   // +1 self loop
}

__global__ void scan1_kernel(const int* __restrict__ deg, int* __restrict__ row_start,
                             int* __restrict__ bsums) {
    __shared__ int s[SCAN_B];
    int t = threadIdx.x;
    int i = blockIdx.x * SCAN_B + t;
    int v = (i < NN) ? deg[i] : 0;
    s[t] = v;
    __syncthreads();
    for (int off = 1; off < SCAN_B; off <<= 1) {
        int u = (t >= off) ? s[t - off] : 0;
        __syncthreads();
        s[t] += u;
        __syncthreads();
    }
    if (i < NN) row_start[i] = s[t] - v;
    if (t == SCAN_B - 1) bsums[blockIdx.x] = s[t];
}

__global__ void scan2_kernel(int* __restrict__ bsums) {
    __shared__ int s[512];
    int t = threadIdx.x;
    int v = (t < NBLK) ? bsums[t] : 0;
    s[t] = v;
    __syncthreads();
    for (int off = 1; off < 512; off <<= 1) {
        int u = (t >= off) ? s[t - off] : 0;
        __syncthreads();
        s[t] += u;
        __syncthreads();
    }
    if (t < NBLK) bsums[t] = s[t] - v;
}

__global__ void scan3_kernel(int* __restrict__ row_start, const int* __restrict__ bsums) {
    int i = blockIdx.x * 256 + threadIdx.x;
    if (i < NN) row_start[i] += bsums[i >> 8];
    if (i == 0) row_start[NN] = NE;
}

__global__ void fill_kernel(const int* __restrict__ src, const int* __restrict__ dst,
                            const float* __restrict__ dinv, const int* __restrict__ row_start,
                            int* __restrict__ tmp, int* __restrict__ csr_src,
                            float* __restrict__ csr_cf) {
    int e = blockIdx.x * 256 + threadIdx.x;
    if (e >= NE) return;
    int d = dst[e], s = src[e];
    int p = atomicAdd(&tmp[d], 1);
    int idx = row_start[d] + p;
    csr_src[idx] = s;
    csr_cf[idx] = dinv[s] * dinv[d];
}

__global__ void gstart_kernel(const int* __restrict__ batch, int* __restrict__ gstart) {
    int n = blockIdx.x * 256 + threadIdx.x;
    if (n >= NN) return;
    int bc = batch[n];
    int bp = (n == 0) ? -1 : batch[n - 1];
    for (int g = bp + 1; g <= bc; ++g) gstart[g] = n;
    if (n == NN - 1)
        for (int g = bc + 1; g <= NG; ++g) gstart[g] = NN;
}

// ---------------- f32 -> bf16 conversion (input x) ----------------

__global__ void cvt_bf16_kernel(const float* __restrict__ in, unsigned short* __restrict__ out,
                                int n4) {
    int i = blockIdx.x * 256 + threadIdx.x;
    if (i >= n4) return;
    float4 v = ((const float4*)in)[i];
    ushort4 o;
    o.x = f2bf(v.x); o.y = f2bf(v.y); o.z = f2bf(v.z); o.w = f2bf(v.w);
    ((ushort4*)out)[i] = o;
}

// ---------------- GCN aggregation: pull-gather on bf16 rows ----------------
// 8 nodes per block, 32 lanes per node, lane covers feats [4*lane .. 4*lane+3]
__launch_bounds__(256)
__global__ void gather_kernel(const int* __restrict__ row_start,
                              const int* __restrict__ csr_src,
                              const float* __restrict__ csr_cf,
                              const unsigned short* __restrict__ xwb,
                              const float* __restrict__ dinv,
                              const float* __restrict__ b,
                              float* __restrict__ agg) {
    int node = blockIdx.x * 8 + (threadIdx.x >> 5);
    int lane = threadIdx.x & 31;
    if (node >= NN) return;
    int rs = row_start[node], re = row_start[node + 1];
    float d = dinv[node];
    float d2 = d * d;
    int fo = lane << 2;
    ushort4 sv = *(const ushort4*)(xwb + (size_t)node * HID + fo);
    float4 acc;
    acc.x = bf2f(sv.x) * d2 + b[fo + 0];
    acc.y = bf2f(sv.y) * d2 + b[fo + 1];
    acc.z = bf2f(sv.z) * d2 + b[fo + 2];
    acc.w = bf2f(sv.w) * d2 + b[fo + 3];
    int e = rs;
    for (; e + 1 < re; e += 2) {
        int s0 = csr_src[e], s1 = csr_src[e + 1];
        float c0 = csr_cf[e], c1 = csr_cf[e + 1];
        ushort4 r0 = *(const ushort4*)(xwb + (size_t)s0 * HID + fo);
        ushort4 r1 = *(const ushort4*)(xwb + (size_t)s1 * HID + fo);
        acc.x += c0 * bf2f(r0.x) + c1 * bf2f(r1.x);
        acc.y += c0 * bf2f(r0.y) + c1 * bf2f(r1.y);
        acc.z += c0 * bf2f(r0.z) + c1 * bf2f(r1.z);
        acc.w += c0 * bf2f(r0.w) + c1 * bf2f(r1.w);
    }
    if (e < re) {
        int s0 = csr_src[e];
        float c0 = csr_cf[e];
        ushort4 r0 = *(const ushort4*)(xwb + (size_t)s0 * HID + fo);
        acc.x += c0 * bf2f(r0.x);
        acc.y += c0 * bf2f(r0.y);
        acc.z += c0 * bf2f(r0.z);
        acc.w += c0 * bf2f(r0.w);
    }
    *(float4*)(agg + (size_t)node * HID + fo) = acc;
}

// ---------------- BatchNorm ----------------

__global__ void bn_stats_kernel(const float* __restrict__ agg,
                                float* __restrict__ gsum, float* __restrict__ gsq) {
    __shared__ float ss[256], sq[256];
    int t = threadIdx.x;
    int f = t & 127;
    int sub = t >> 7;
    float s = 0.f, q = 0.f;
    for (int r = blockIdx.x * 2 + sub; r < NN; r += gridDim.x * 2) {
        float v = agg[(size_t)r * HID + f];
        s += v; q += v * v;
    }
    ss[t] = s; sq[t] = q;
    __syncthreads();
    if (t < 128) {
        atomicAdd(&gsum[f], ss[t] + ss[t + 128]);
        atomicAdd(&gsq[f],  sq[t] + sq[t + 128]);
    }
}

__global__ void bn_finalize_kernel(const float* __restrict__ gsum, const float* __restrict__ gsq,
                                   const float* __restrict__ g, const float* __restrict__ be,
                                   float* __restrict__ scale, float* __restrict__ shift) {
    int f = threadIdx.x;
    float mu = gsum[f] * (1.0f / NN);
    float var = gsq[f] * (1.0f / NN) - mu * mu;
    float sc = g[f] * rsqrtf(var + BN_EPS);
    scale[f] = sc;
    shift[f] = be[f] - mu * sc;
}

// out_x = relu(bn(agg)) -> bf16
__global__ void bn_apply_relu_kernel(const float* __restrict__ agg,
                                     unsigned short* __restrict__ aggb,
                                     const float* __restrict__ scale,
                                     const float* __restrict__ shift) {
    int i = blockIdx.x * 256 + threadIdx.x;
    if (i >= NN * 32) return;
    int c = (i & 31) << 2;
    float4 v = ((const float4*)agg)[i];
    ushort4 o;
    o.x = f2bf(fmaxf(v.x * scale[c + 0] + shift[c + 0], 0.f));
    o.y = f2bf(fmaxf(v.y * scale[c + 1] + shift[c + 1], 0.f));
    o.z = f2bf(fmaxf(v.z * scale[c + 2] + shift[c + 2], 0.f));
    o.w = f2bf(fmaxf(v.w * scale[c + 3] + shift[c + 3], 0.f));
    ((ushort4*)aggb)[i] = o;
}

// ---------------- MFMA GEMM (bf16 in, f32 acc, bf16 out) ----------------
// Block: 256 thr / 4 waves; tile 128 rows x 128 cols; wave owns 32 rows.
// mode 2: target = bf16(A1 @ Wa)                                   (K1 in {64,128})
// mode 1: t = A1@Wa + A2@Wb + bias1 + bias2; z = sigmoid(t);
//         target = bf16(z*outx + (1-z)*target)    (target aliases A2; per-wave rows disjoint)
// W staged once per block into LDS, k-chunked: WT[chunk][n][8 k] bf16 -> conflict-free b128 frags.
__launch_bounds__(256, 2)
__global__ void mgemm_kernel(const unsigned short* __restrict__ A1,
                             const float* __restrict__ Wa, int K1,
                             const unsigned short* A2,
                             const float* __restrict__ Wb, int K2,
                             const float* __restrict__ bias1, const float* __restrict__ bias2,
                             const unsigned short* outx,
                             unsigned short* target, int mode) {
    __shared__ unsigned short WT[2][16384];   // 2 matrices x 16 chunks x 128 n x 8 = 64 KB
    int tid = threadIdx.x;

    // ---- stage W (f32 global -> bf16 LDS, transposed+chunked) ----
    for (int p = 0; p < 2; ++p) {
        const float* W = p ? Wb : Wa;
        int K = p ? K2 : K1;
        if (K == 0) continue;
        unsigned int* wt32 = (unsigned int*)WT[p];
        for (int idx = tid; idx < K * 8; idx += 256) {
            int k = (idx >> 4) << 1;            // even k
            int n0 = (idx & 15) << 3;
            float4 w00 = *(const float4*)(W + (size_t)k * HID + n0);
            float4 w01 = *(const float4*)(W + (size_t)k * HID + n0 + 4);
            float4 w10 = *(const float4*)(W + (size_t)(k + 1) * HID + n0);
            float4 w11 = *(const float4*)(W + (size_t)(k + 1) * HID + n0 + 4);
            float a0[8] = {w00.x, w00.y, w00.z, w00.w, w01.x, w01.y, w01.z, w01.w};
            float a1[8] = {w10.x, w10.y, w10.z, w10.w, w11.x, w11.y, w11.z, w11.w};
            int c = k >> 3, kj2 = (k & 7) >> 1;
#pragma unroll
            for (int j = 0; j < 8; ++j) {
                unsigned int pk = (unsigned int)f2bf(a0[j]) |
                                  ((unsigned int)f2bf(a1[j]) << 16);
                wt32[(c * 128 + n0 + j) * 4 + kj2] = pk;
            }
        }
    }
    __syncthreads();

    int lane = tid & 63;
    int wv = tid >> 6;
    int lane15 = lane & 15;
    int q = lane >> 4;                          // 0..3
    int m0 = blockIdx.x * 128 + wv * 32;

    f32x4 acc[2][8];
#pragma unroll
    for (int r = 0; r < 2; ++r)
#pragma unroll
        for (int nt = 0; nt < 8; ++nt)
            acc[r][nt] = (f32x4){0.f, 0.f, 0.f, 0.f};

    bf16x8 zfrag = {0, 0, 0, 0, 0, 0, 0, 0};

    // ---- K loop (no barriers; W is read-only in LDS) ----
    for (int p = 0; p < 2; ++p) {
        const unsigned short* A = p ? A2 : A1;
        int K = p ? K2 : K1;
        if (K == 0) continue;
        int row0 = m0 + lane15;
        const unsigned short* a0p = A + (size_t)row0 * K + (q << 3);
        const unsigned short* a1p = a0p + (size_t)16 * K;
        bool g0 = row0 < NN, g1 = (row0 + 16) < NN;
        for (int k0 = 0; k0 < K; k0 += 32) {
            bf16x8 af0 = zfrag, af1 = zfrag;
            if (g0) af0 = *(const bf16x8*)(a0p + k0);
            if (g1) af1 = *(const bf16x8*)(a1p + k0);
            const unsigned short* wbase =
                &WT[p][(size_t)(((k0 >> 3) + q) * 128 + lane15) * 8];
#pragma unroll
            for (int nt = 0; nt < 8; ++nt) {
                bf16x8 bf = *(const bf16x8*)(wbase + nt * 128);
                acc[0][nt] = __builtin_amdgcn_mfma_f32_16x16x32_bf16(af0, bf, acc[0][nt], 0, 0, 0);
                acc[1][nt] = __builtin_amdgcn_mfma_f32_16x16x32_bf16(af1, bf, acc[1][nt], 0, 0, 0);
            }
        }
    }

    // ---- epilogue: C/D layout col=lane&15, row=q*4+reg ----
    if (mode == 2) {
#pragma unroll
        for (int r = 0; r < 2; ++r)
#pragma unroll
            for (int nt = 0; nt < 8; ++nt) {
                int col = nt * 16 + lane15;
#pragma unroll
                for (int g = 0; g < 4; ++g) {
                    int row = m0 + r * 16 + q * 4 + g;
                    if (row < NN)
                        target[(size_t)row * HID + col] = f2bf(acc[r][nt][g]);
                }
            }
    } else {
        float bsum[8];
#pragma unroll
        for (int nt = 0; nt < 8; ++nt) {
            int col = nt * 16 + lane15;
            bsum[nt] = bias1[col] + bias2[col];
        }
#pragma unroll
        for (int r = 0; r < 2; ++r)
#pragma unroll
            for (int nt = 0; nt < 8; ++nt) {
                int col = nt * 16 + lane15;
#pragma unroll
                for (int g = 0; g < 4; ++g) {
                    int row = m0 + r * 16 + q * 4 + g;
                    if (row < NN) {
                        size_t off = (size_t)row * HID + col;
                        float t = acc[r][nt][g] + bsum[nt];
                        float z = 1.0f / (1.0f + expf(-t));
                        float ox = bf2f(outx[off]);
                        float ix = bf2f(target[off]);
                        target[off] = f2bf(z * ox + (1.0f - z) * ix);
                    }
                }
            }
    }
}

// ---------------- pooling (segment-based, bf16 input) ----------------

__global__ void pool_kernel(const unsigned short* __restrict__ h,
                            const int* __restrict__ gstart,
                            float* __restrict__ pool) {
    __shared__ float red[8][128];
    int g = blockIdx.x, t = threadIdx.x;
    int lane = t & 31, sub = t >> 5;
    int s = gstart[g], e = gstart[g + 1];
    float4 acc = make_float4(0.f, 0.f, 0.f, 0.f);
    for (int r = s + sub; r < e; r += 8) {
        ushort4 v = *(const ushort4*)(h + (size_t)r * HID + (lane << 2));
        acc.x += bf2f(v.x); acc.y += bf2f(v.y);
        acc.z += bf2f(v.z); acc.w += bf2f(v.w);
    }
    *(float4*)&red[sub][lane << 2] = acc;
    __syncthreads();
    if (t < 128) {
        float a = 0.f;
#pragma unroll
        for (int i = 0; i < 8; ++i) a += red[i][t];
        pool[(size_t)g * HID + t] = a / (float)max(e - s, 1);
    }
}

// ---------------- MLP head ----------------

__global__ void head_kernel(const float* __restrict__ pool1, const float* __restrict__ pool2,
                            const float* __restrict__ pool3,
                            const float* __restrict__ eF,
                            const float* __restrict__ fc1W, const float* __restrict__ fc1b,
                            const float* __restrict__ fc3W, const float* __restrict__ fc3b,
                            float* __restrict__ out) {
    __shared__ float hg[3 * HID + EXD];
    __shared__ float hh[HID];
    int g = blockIdx.x, t = threadIdx.x;
    hg[t]           = pool1[(size_t)g * HID + t];
    hg[HID + t]     = pool2[(size_t)g * HID + t];
    hg[2 * HID + t] = pool3[(size_t)g * HID + t];
    if (t < EXD) hg[3 * HID + t] = eF[(size_t)g * EXD + t];
    __syncthreads();
    float acc = fc1b[t];
    for (int k = 0; k < 3 * HID + EXD; ++k) acc += hg[k] * fc1W[(size_t)k * HID + t];
    hh[t] = fmaxf(acc, 0.f);
    __syncthreads();
    if (t < OUTD) {
        float a2 = fc3b[t];
        for (int k = 0; k < HID; ++k) a2 += hh[k] * fc3W[(size_t)k * OUTD + t];
        out[(size_t)g * OUTD + t] = a2;
    }
}

// ---------------- launch ----------------

extern "C" void kernel_launch(void* const* d_in, const int* in_sizes, int n_in,
                              void* d_out, int out_size, void* d_ws, size_t ws_size,
                              hipStream_t stream) {
    const float* x      = (const float*)d_in[0];
    const float* eF     = (const float*)d_in[1];
    const int*   ei     = (const int*)d_in[2];
    const int*   batch  = (const int*)d_in[3];
    const int* src = ei;
    const int* dst = ei + NE;

    const float* W1 = (const float*)d_in[4];  const float* b1 = (const float*)d_in[5];
    const float* W2 = (const float*)d_in[6];  const float* b2 = (const float*)d_in[7];
    const float* W3 = (const float*)d_in[8];  const float* b3 = (const float*)d_in[9];
    const float* g1 = (const float*)d_in[10]; const float* be1 = (const float*)d_in[11];
    const float* g2 = (const float*)d_in[12]; const float* be2 = (const float*)d_in[13];
    const float* g3 = (const float*)d_in[14]; const float* be3 = (const float*)d_in[15];
    const float* s1_Wp = (const float*)d_in[16];
    const float* s1_Wi = (const float*)d_in[17]; const float* s1_bi = (const float*)d_in[18];
    const float* s1_Wo = (const float*)d_in[19]; const float* s1_bo = (const float*)d_in[20];
    const float* s2_Wi = (const float*)d_in[21]; const float* s2_bi = (const float*)d_in[22];
    const float* s2_Wo = (const float*)d_in[23]; const float* s2_bo = (const float*)d_in[24];
    const float* s3_Wi = (const float*)d_in[25]; const float* s3_bi = (const float*)d_in[26];
    const float* s3_Wo = (const float*)d_in[27]; const float* s3_bo = (const float*)d_in[28];
    const float* fc1W = (const float*)d_in[29]; const float* fc1b = (const float*)d_in[30];
    const float* fc3W = (const float*)d_in[31]; const float* fc3b = (const float*)d_in[32];

    float* ws = (float*)d_ws;
    size_t S = (size_t)NN * HID;
    // bf16 node matrices
    unsigned short* xwb  = (unsigned short*)ws;            // NN*HID
    unsigned short* xb   = xwb + S;                        // NN*IN_DIM
    unsigned short* hb   = xb + (size_t)NN * IN_DIM;       // NN*HID
    unsigned short* aggb = hb + S;                         // NN*HID
    float* agg = (float*)(aggb + S);                       // NN*HID f32
    float* dinv = agg + S;                                 // NN
    int*   row_start = (int*)(dinv + NN);                  // NN+1
    int*   csr_src   = row_start + NN + 1;                 // NE
    float* csr_cf    = (float*)(csr_src + NE);             // NE
    int*   gstart    = (int*)(csr_cf + NE);                // NG+1
    float* gsum = (float*)(gstart + NG + 1);
    float* gsq  = gsum + HID;
    float* scl  = gsq + HID;
    float* shf  = scl + HID;
    float* pools = shf + HID;                              // 3*NG*HID
    // transient (aliased into xwb region, dead before first mgemm writes xwb)
    int* deg   = (int*)ws;                                 // NN
    int* tmp   = (int*)ws + NN;                            // NN
    int* bsums = (int*)ws + 2 * NN;                        // NBLK

    const int TB = 256;
    const int GB2 = (NN + 127) / 128;            // mgemm blocks
    const int EL  = (NN * 32 + TB - 1) / TB;
    const int EB  = (NE + TB - 1) / TB;
    const int NB  = (NN + TB - 1) / TB;
    const int AGB = (NN + 7) / 8;
    const int CV  = (NN * 16 + TB - 1) / TB;     // x cvt float4 blocks

    // ---- CSR build + graph offsets + x->bf16 ----
    hipMemsetAsync(deg, 0, 2 * NN * sizeof(int), stream);
    deg_kernel<<<EB, TB, 0, stream>>>(dst, deg);
    dinv_kernel<<<NB, TB, 0, stream>>>(deg, dinv);
    scan1_kernel<<<NBLK, SCAN_B, 0, stream>>>(deg, row_start, bsums);
    scan2_kernel<<<1, 512, 0, stream>>>(bsums);
    scan3_kernel<<<NB, TB, 0, stream>>>(row_start, bsums);
    fill_kernel<<<EB, TB, 0, stream>>>(src, dst, dinv, row_start, tmp, csr_src, csr_cf);
    gstart_kernel<<<NB, TB, 0, stream>>>(batch, gstart);
    cvt_bf16_kernel<<<CV, TB, 0, stream>>>(x, xb, NN * 16);

    // ---- layer 1 ----
    mgemm_kernel<<<GB2, TB, 0, stream>>>(xb, W1, IN_DIM, nullptr, nullptr, 0,
                                         nullptr, nullptr, nullptr, xwb, 2);
    mgemm_kernel<<<GB2, TB, 0, stream>>>(xb, s1_Wp, IN_DIM, nullptr, nullptr, 0,
                                         nullptr, nullptr, nullptr, hb, 2);   // in_x
    gather_kernel<<<AGB, TB, 0, stream>>>(row_start, csr_src, csr_cf, xwb, dinv, b1, agg);
    hipMemsetAsync(gsum, 0, 2 * HID * sizeof(float), stream);
    bn_stats_kernel<<<1024, TB, 0, stream>>>(agg, gsum, gsq);
    bn_finalize_kernel<<<1, HID, 0, stream>>>(gsum, gsq, g1, be1, scl, shf);
    bn_apply_relu_kernel<<<EL, TB, 0, stream>>>(agg, aggb, scl, shf);
    mgemm_kernel<<<GB2, TB, 0, stream>>>(aggb, s1_Wo, HID, hb, s1_Wi, HID,
                                         s1_bo, s1_bi, aggb, hb, 1);
    pool_kernel<<<NG, TB, 0, stream>>>(hb, gstart, pools);

    // ---- layer 2 ----
    mgemm_kernel<<<GB2, TB, 0, stream>>>(hb, W2, HID, nullptr, nullptr, 0,
                                         nullptr, nullptr, nullptr, xwb, 2);
    gather_kernel<<<AGB, TB, 0, stream>>>(row_start, csr_src, csr_cf, xwb, dinv, b2, agg);
    hipMemsetAsync(gsum, 0, 2 * HID * sizeof(float), stream);
    bn_stats_kernel<<<1024, TB, 0, stream>>>(agg, gsum, gsq);
    bn_finalize_kernel<<<1, HID, 0, stream>>>(gsum, gsq, g2, be2, scl, shf);
    bn_apply_relu_kernel<<<EL, TB, 0, stream>>>(agg, aggb, scl, shf);
    mgemm_kernel<<<GB2, TB, 0, stream>>>(aggb, s2_Wo, HID, hb, s2_Wi, HID,
                                         s2_bo, s2_bi, aggb, hb, 1);
    pool_kernel<<<NG, TB, 0, stream>>>(hb, gstart, pools + (size_t)NG * HID);

    // ---- layer 3 ----
    mgemm_kernel<<<GB2, TB, 0, stream>>>(hb, W3, HID, nullptr, nullptr, 0,
                                         nullptr, nullptr, nullptr, xwb, 2);
    gather_kernel<<<AGB, TB, 0, stream>>>(row_start, csr_src, csr_cf, xwb, dinv, b3, agg);
    hipMemsetAsync(gsum, 0, 2 * HID * sizeof(float), stream);
    bn_stats_kernel<<<1024, TB, 0, stream>>>(agg, gsum, gsq);
    bn_finalize_kernel<<<1, HID, 0, stream>>>(gsum, gsq, g3, be3, scl, shf);
    bn_apply_relu_kernel<<<EL, TB, 0, stream>>>(agg, aggb, scl, shf);
    mgemm_kernel<<<GB2, TB, 0, stream>>>(aggb, s3_Wo, HID, hb, s3_Wi, HID,
                                         s3_bo, s3_bi, aggb, hb, 1);
    pool_kernel<<<NG, TB, 0, stream>>>(hb, gstart, pools + 2 * (size_t)NG * HID);

    // ---- head ----
    head_kernel<<<NG, HID, 0, stream>>>(pools, pools + (size_t)NG * HID,
                                        pools + 2 * (size_t)NG * HID, eF,
                                        fc1W, fc1b, fc3W, fc3b, (float*)d_out);
}

// Round 5
// 899.078 us; speedup vs baseline: 10.7750x; 1.1153x over previous
//
#include <hip/hip_runtime.h>
#include <math.h>

#define NN 100000
#define NE 1600000
#define NG 1000
#define IN_DIM 64
#define HID 128
#define EXD 32
#define OUTD 10
#define BN_EPS 1e-5f

#define SCAN_B 256
#define NBLK ((NN + SCAN_B - 1) / SCAN_B)   // 391

typedef __attribute__((ext_vector_type(8))) short bf16x8;
typedef __attribute__((ext_vector_type(4))) float f32x4;

__device__ __forceinline__ float bf2f(unsigned short h) {
    return __uint_as_float((unsigned int)h << 16);
}
__device__ __forceinline__ unsigned short f2bf(float f) {
    unsigned int u = __float_as_uint(f);
    u += 0x7fffu + ((u >> 16) & 1u);        // round to nearest even
    return (unsigned short)(u >> 16);
}

// ---------------- degree / CSR build (layer-invariant) ----------------

__global__ void deg_kernel(const int* __restrict__ dst, int* __restrict__ deg) {
    int e = blockIdx.x * 256 + threadIdx.x;
    if (e < NE) atomicAdd(&deg[dst[e]], 1);
}

__global__ void dinv_kernel(const int* __restrict__ deg, float* __restrict__ dinv) {
    int i = blockIdx.x * 256 + threadIdx.x;
    if (i < NN) dinv[i] = rsqrtf((float)deg[i] + 1.0f);   // +1 self loop
}

__global__ void scan1_kernel(const int* __restrict__ deg, int* __restrict__ row_start,
                             int* __restrict__ bsums) {
    __shared__ int s[SCAN_B];
    int t = threadIdx.x;
    int i = blockIdx.x * SCAN_B + t;
    int v = (i < NN) ? deg[i] : 0;
    s[t] = v;
    __syncthreads();
    for (int off = 1; off < SCAN_B; off <<= 1) {
        int u = (t >= off) ? s[t - off] : 0;
        __syncthreads();
        s[t] += u;
        __syncthreads();
    }
    if (i < NN) row_start[i] = s[t] - v;
    if (t == SCAN_B - 1) bsums[blockIdx.x] = s[t];
}

__global__ void scan2_kernel(int* __restrict__ bsums) {
    __shared__ int s[512];
    int t = threadIdx.x;
    int v = (t < NBLK) ? bsums[t] : 0;
    s[t] = v;
    __syncthreads();
    for (int off = 1; off < 512; off <<= 1) {
        int u = (t >= off) ? s[t - off] : 0;
        __syncthreads();
        s[t] += u;
        __syncthreads();
    }
    if (t < NBLK) bsums[t] = s[t] - v;
}

__global__ void scan3_kernel(int* __restrict__ row_start, const int* __restrict__ bsums) {
    int i = blockIdx.x * 256 + threadIdx.x;
    if (i < NN) row_start[i] += bsums[i >> 8];
    if (i == 0) row_start[NN] = NE;
}

// place each edge into its dst bucket (src only; coef folded into gather)
__global__ void fill_kernel(const int* __restrict__ src, const int* __restrict__ dst,
                            const int* __restrict__ row_start,
                            int* __restrict__ tmp, int* __restrict__ csr_src) {
    int e = blockIdx.x * 256 + threadIdx.x;
    if (e >= NE) return;
    int d = dst[e], s = src[e];
    int p = atomicAdd(&tmp[d], 1);
    csr_src[row_start[d] + p] = s;
}

__global__ void gstart_kernel(const int* __restrict__ batch, int* __restrict__ gstart) {
    int n = blockIdx.x * 256 + threadIdx.x;
    if (n >= NN) return;
    int bc = batch[n];
    int bp = (n == 0) ? -1 : batch[n - 1];
    for (int g = bp + 1; g <= bc; ++g) gstart[g] = n;
    if (n == NN - 1)
        for (int g = bc + 1; g <= NG; ++g) gstart[g] = NN;
}

// ---------------- f32 -> bf16 conversion (input x) ----------------

__global__ void cvt_bf16_kernel(const float* __restrict__ in, unsigned short* __restrict__ out,
                                int n4) {
    int i = blockIdx.x * 256 + threadIdx.x;
    if (i >= n4) return;
    float4 v = ((const float4*)in)[i];
    ushort4 o;
    o.x = f2bf(v.x); o.y = f2bf(v.y); o.z = f2bf(v.z); o.w = f2bf(v.w);
    ((ushort4*)out)[i] = o;
}

// ---------------- weight prep: f32 -> bf16 frag layout ----------------
// wf[m*16384 + ((k>>3)*128 + n)*8 + (k&7)]
struct WPack {
    const float* w[10];
    int K[10];
};

__global__ void wprep_kernel(WPack p, unsigned short* __restrict__ wf) {
    int m = blockIdx.y;
    int idx = blockIdx.x * 256 + threadIdx.x;
    int K = p.K[m];
    if (idx >= K * 128) return;
    int k = idx >> 7, n = idx & 127;
    wf[m * 16384 + (((k >> 3) * 128 + n) << 3) + (k & 7)] = f2bf(p.w[m][idx]);
}

// ---------------- GCN aggregation: pull-gather, bf16 rows, bf16 out ----------------
// 8 nodes per block, 32 lanes per node, lane covers feats [4*lane .. 4*lane+3]
// aggb[n,:] = bf16( dinv[n] * sum_e dinv[src_e]*xwb[src_e,:] + dinv[n]^2*xwb[n,:] + b )
__launch_bounds__(256)
__global__ void gather_kernel(const int* __restrict__ row_start,
                              const int* __restrict__ csr_src,
                              const unsigned short* __restrict__ xwb,
                              const float* __restrict__ dinv,
                              const float* __restrict__ b,
                              unsigned short* __restrict__ aggb) {
    int node = blockIdx.x * 8 + (threadIdx.x >> 5);
    int lane = threadIdx.x & 31;
    if (node >= NN) return;
    int rs = row_start[node], re = row_start[node + 1];
    float d = dinv[node];
    int fo = lane << 2;
    ushort4 sv = *(const ushort4*)(xwb + (size_t)node * HID + fo);
    float4 accE = make_float4(0.f, 0.f, 0.f, 0.f);
    int e = rs;
    for (; e + 3 < re; e += 4) {
        int s0 = csr_src[e], s1 = csr_src[e + 1], s2 = csr_src[e + 2], s3 = csr_src[e + 3];
        float c0 = dinv[s0], c1 = dinv[s1], c2 = dinv[s2], c3 = dinv[s3];
        ushort4 r0 = *(const ushort4*)(xwb + (size_t)s0 * HID + fo);
        ushort4 r1 = *(const ushort4*)(xwb + (size_t)s1 * HID + fo);
        ushort4 r2 = *(const ushort4*)(xwb + (size_t)s2 * HID + fo);
        ushort4 r3 = *(const ushort4*)(xwb + (size_t)s3 * HID + fo);
        accE.x += c0 * bf2f(r0.x) + c1 * bf2f(r1.x) + c2 * bf2f(r2.x) + c3 * bf2f(r3.x);
        accE.y += c0 * bf2f(r0.y) + c1 * bf2f(r1.y) + c2 * bf2f(r2.y) + c3 * bf2f(r3.y);
        accE.z += c0 * bf2f(r0.z) + c1 * bf2f(r1.z) + c2 * bf2f(r2.z) + c3 * bf2f(r3.z);
        accE.w += c0 * bf2f(r0.w) + c1 * bf2f(r1.w) + c2 * bf2f(r2.w) + c3 * bf2f(r3.w);
    }
    for (; e < re; ++e) {
        int s0 = csr_src[e];
        float c0 = dinv[s0];
        ushort4 r0 = *(const ushort4*)(xwb + (size_t)s0 * HID + fo);
        accE.x += c0 * bf2f(r0.x);
        accE.y += c0 * bf2f(r0.y);
        accE.z += c0 * bf2f(r0.z);
        accE.w += c0 * bf2f(r0.w);
    }
    float d2 = d * d;
    ushort4 o;
    o.x = f2bf(d * accE.x + d2 * bf2f(sv.x) + b[fo + 0]);
    o.y = f2bf(d * accE.y + d2 * bf2f(sv.y) + b[fo + 1]);
    o.z = f2bf(d * accE.z + d2 * bf2f(sv.z) + b[fo + 2]);
    o.w = f2bf(d * accE.w + d2 * bf2f(sv.w) + b[fo + 3]);
    *(ushort4*)(aggb + (size_t)node * HID + fo) = o;
}

// ---------------- BatchNorm (bf16 agg) ----------------

__global__ void bn_stats_kernel(const unsigned short* __restrict__ aggb,
                                float* __restrict__ gsum, float* __restrict__ gsq) {
    __shared__ float ss[4][128], sq[4][128];
    int t = threadIdx.x;
    int fp = (t & 63) << 1;     // feature pair base
    int sub = t >> 6;           // 0..3
    float s0 = 0.f, s1 = 0.f, q0 = 0.f, q1 = 0.f;
    for (int r = blockIdx.x * 4 + sub; r < NN; r += 4096) {
        unsigned int u = *(const unsigned int*)(aggb + (size_t)r * HID + fp);
        float v0 = bf2f((unsigned short)(u & 0xffffu));
        float v1 = bf2f((unsigned short)(u >> 16));
        s0 += v0; q0 += v0 * v0;
        s1 += v1; q1 += v1 * v1;
    }
    ss[sub][fp] = s0; ss[sub][fp + 1] = s1;
    sq[sub][fp] = q0; sq[sub][fp + 1] = q1;
    __syncthreads();
    if (t < 128) {
        atomicAdd(&gsum[t], ss[0][t] + ss[1][t] + ss[2][t] + ss[3][t]);
        atomicAdd(&gsq[t],  sq[0][t] + sq[1][t] + sq[2][t] + sq[3][t]);
    }
}

__global__ void bn_finalize_kernel(const float* __restrict__ gsum, const float* __restrict__ gsq,
                                   const float* __restrict__ g, const float* __restrict__ be,
                                   float* __restrict__ scale, float* __restrict__ shift) {
    int f = threadIdx.x;
    float mu = gsum[f] * (1.0f / NN);
    float var = gsq[f] * (1.0f / NN) - mu * mu;
    float sc = g[f] * rsqrtf(var + BN_EPS);
    scale[f] = sc;
    shift[f] = be[f] - mu * sc;
}

// aggb = bf16(relu(bn(aggb))) in place
__global__ void bn_apply_relu_kernel(unsigned short* __restrict__ aggb,
                                     const float* __restrict__ scale,
                                     const float* __restrict__ shift) {
    int i = blockIdx.x * 256 + threadIdx.x;     // over NN*16 ushort8 chunks
    if (i >= NN * 16) return;
    int c = (i & 15) << 3;
    bf16x8 v = ((const bf16x8*)aggb)[i];
    bf16x8 o;
#pragma unroll
    for (int j = 0; j < 8; ++j)
        o[j] = (short)f2bf(fmaxf(bf2f((unsigned short)v[j]) * scale[c + j] + shift[c + j], 0.f));
    ((bf16x8*)aggb)[i] = o;
}

// ---------------- MFMA GEMM (bf16 in, f32 acc, bf16 out) ----------------
// Block: 256 thr / 4 waves; tile 128 rows x 128 cols; wave owns 32 rows in K-loop.
// B-frags read directly from pre-transformed global wf (L2-hot). No LDS in K-loop.
// Epilogue stages C tile in LDS (bf16, padded stride) for coalesced 16B global I/O.
// mode 2: target = bf16(A1 @ Wa)
// mode 1: t = A1@Wa + A2@Wb + bias1 + bias2; z = sigmoid(t);
//         target = bf16(z*outx + (1-z)*target)   (target aliases A2; block rows disjoint)
#define CS_STRIDE 136
__launch_bounds__(256, 2)
__global__ void mgemm_kernel(const unsigned short* __restrict__ A1,
                             const unsigned short* __restrict__ wfA, int K1,
                             const unsigned short* A2,
                             const unsigned short* __restrict__ wfB, int K2,
                             const float* __restrict__ bias1, const float* __restrict__ bias2,
                             const unsigned short* outx,
                             unsigned short* target, int mode) {
    __shared__ unsigned short cs[128 * CS_STRIDE];
    int tid = threadIdx.x;
    int lane = tid & 63;
    int wv = tid >> 6;
    int lane15 = lane & 15;
    int q = lane >> 4;
    int m0 = blockIdx.x * 128 + wv * 32;

    f32x4 acc[2][8];
#pragma unroll
    for (int r = 0; r < 2; ++r)
#pragma unroll
        for (int nt = 0; nt < 8; ++nt)
            acc[r][nt] = (f32x4){0.f, 0.f, 0.f, 0.f};

    bf16x8 zf = {0, 0, 0, 0, 0, 0, 0, 0};

    for (int p = 0; p < 2; ++p) {
        const unsigned short* A = p ? A2 : A1;
        const unsigned short* wf = p ? wfB : wfA;
        int K = p ? K2 : K1;
        if (K == 0) continue;
        int row0 = m0 + lane15;
        const unsigned short* a0p = A + (size_t)row0 * K + (q << 3);
        const unsigned short* a1p = a0p + (size_t)16 * K;
        bool g0 = row0 < NN, g1 = (row0 + 16) < NN;
#pragma unroll 4
        for (int k0 = 0; k0 < K; k0 += 32) {
            bf16x8 af0 = zf, af1 = zf;
            if (g0) af0 = *(const bf16x8*)(a0p + k0);
            if (g1) af1 = *(const bf16x8*)(a1p + k0);
            const unsigned short* wb = wf + (((k0 >> 3) + q) << 10) + (lane15 << 3);
#pragma unroll
            for (int nt = 0; nt < 8; ++nt) {
                bf16x8 bf = *(const bf16x8*)(wb + nt * 128);
                acc[0][nt] = __builtin_amdgcn_mfma_f32_16x16x32_bf16(af0, bf, acc[0][nt], 0, 0, 0);
                acc[1][nt] = __builtin_amdgcn_mfma_f32_16x16x32_bf16(af1, bf, acc[1][nt], 0, 0, 0);
            }
        }
    }

    // ---- stage C tile into LDS (C/D layout: col=lane15, row=q*4+g) ----
    if (mode == 1) {
        float bsum[8];
#pragma unroll
        for (int nt = 0; nt < 8; ++nt)
            bsum[nt] = bias1[nt * 16 + lane15] + bias2[nt * 16 + lane15];
#pragma unroll
        for (int r = 0; r < 2; ++r)
#pragma unroll
            for (int nt = 0; nt < 8; ++nt)
#pragma unroll
                for (int g = 0; g < 4; ++g) {
                    int rr = wv * 32 + r * 16 + q * 4 + g;
                    cs[rr * CS_STRIDE + nt * 16 + lane15] = f2bf(acc[r][nt][g] + bsum[nt]);
                }
    } else {
#pragma unroll
        for (int r = 0; r < 2; ++r)
#pragma unroll
            for (int nt = 0; nt < 8; ++nt)
#pragma unroll
                for (int g = 0; g < 4; ++g) {
                    int rr = wv * 32 + r * 16 + q * 4 + g;
                    cs[rr * CS_STRIDE + nt * 16 + lane15] = f2bf(acc[r][nt][g]);
                }
    }
    __syncthreads();

    // ---- coalesced global epilogue: thread covers (row, 8-col chunk) ----
#pragma unroll
    for (int i = 0; i < 8; ++i) {
        int rt = (tid >> 4) + i * 16;
        int ch = tid & 15;
        int row = blockIdx.x * 128 + rt;
        if (row >= NN) continue;
        bf16x8 c = *(const bf16x8*)(cs + rt * CS_STRIDE + (ch << 3));
        size_t off = (size_t)row * HID + (ch << 3);
        if (mode == 1) {
            bf16x8 oxv = *(const bf16x8*)(outx + off);
            bf16x8 ixv = *(const bf16x8*)(target + off);
            bf16x8 o;
#pragma unroll
            for (int j = 0; j < 8; ++j) {
                float t = bf2f((unsigned short)c[j]);
                float z = 1.0f / (1.0f + expf(-t));
                float h = z * bf2f((unsigned short)oxv[j]) +
                          (1.0f - z) * bf2f((unsigned short)ixv[j]);
                o[j] = (short)f2bf(h);
            }
            *(bf16x8*)(target + off) = o;
        } else {
            *(bf16x8*)(target + off) = c;
        }
    }
}

// ---------------- pooling (segment-based, bf16 input) ----------------

__global__ void pool_kernel(const unsigned short* __restrict__ h,
                            const int* __restrict__ gstart,
                            float* __restrict__ pool) {
    __shared__ float red[8][128];
    int g = blockIdx.x, t = threadIdx.x;
    int lane = t & 31, sub = t >> 5;
    int s = gstart[g], e = gstart[g + 1];
    float4 acc = make_float4(0.f, 0.f, 0.f, 0.f);
    for (int r = s + sub; r < e; r += 8) {
        ushort4 v = *(const ushort4*)(h + (size_t)r * HID + (lane << 2));
        acc.x += bf2f(v.x); acc.y += bf2f(v.y);
        acc.z += bf2f(v.z); acc.w += bf2f(v.w);
    }
    *(float4*)&red[sub][lane << 2] = acc;
    __syncthreads();
    if (t < 128) {
        float a = 0.f;
#pragma unroll
        for (int i = 0; i < 8; ++i) a += red[i][t];
        pool[(size_t)g * HID + t] = a / (float)max(e - s, 1);
    }
}

// ---------------- MLP head ----------------

__global__ void head_kernel(const float* __restrict__ pool1, const float* __restrict__ pool2,
                            const float* __restrict__ pool3,
                            const float* __restrict__ eF,
                            const float* __restrict__ fc1W, const float* __restrict__ fc1b,
                            const float* __restrict__ fc3W, const float* __restrict__ fc3b,
                            float* __restrict__ out) {
    __shared__ float hg[3 * HID + EXD];
    __shared__ float hh[HID];
    int g = blockIdx.x, t = threadIdx.x;
    hg[t]           = pool1[(size_t)g * HID + t];
    hg[HID + t]     = pool2[(size_t)g * HID + t];
    hg[2 * HID + t] = pool3[(size_t)g * HID + t];
    if (t < EXD) hg[3 * HID + t] = eF[(size_t)g * EXD + t];
    __syncthreads();
    float acc = fc1b[t];
    for (int k = 0; k < 3 * HID + EXD; ++k) acc += hg[k] * fc1W[(size_t)k * HID + t];
    hh[t] = fmaxf(acc, 0.f);
    __syncthreads();
    if (t < OUTD) {
        float a2 = fc3b[t];
        for (int k = 0; k < HID; ++k) a2 += hh[k] * fc3W[(size_t)k * OUTD + t];
        out[(size_t)g * OUTD + t] = a2;
    }
}

// ---------------- launch ----------------

extern "C" void kernel_launch(void* const* d_in, const int* in_sizes, int n_in,
                              void* d_out, int out_size, void* d_ws, size_t ws_size,
                              hipStream_t stream) {
    const float* x      = (const float*)d_in[0];
    const float* eF     = (const float*)d_in[1];
    const int*   ei     = (const int*)d_in[2];
    const int*   batch  = (const int*)d_in[3];
    const int* src = ei;
    const int* dst = ei + NE;

    const float* W1 = (const float*)d_in[4];  const float* b1 = (const float*)d_in[5];
    const float* W2 = (const float*)d_in[6];  const float* b2 = (const float*)d_in[7];
    const float* W3 = (const float*)d_in[8];  const float* b3 = (const float*)d_in[9];
    const float* g1 = (const float*)d_in[10]; const float* be1 = (const float*)d_in[11];
    const float* g2 = (const float*)d_in[12]; const float* be2 = (const float*)d_in[13];
    const float* g3 = (const float*)d_in[14]; const float* be3 = (const float*)d_in[15];
    const float* s1_Wp = (const float*)d_in[16];
    const float* s1_Wi = (const float*)d_in[17]; const float* s1_bi = (const float*)d_in[18];
    const float* s1_Wo = (const float*)d_in[19]; const float* s1_bo = (const float*)d_in[20];
    const float* s2_Wi = (const float*)d_in[21]; const float* s2_bi = (const float*)d_in[22];
    const float* s2_Wo = (const float*)d_in[23]; const float* s2_bo = (const float*)d_in[24];
    const float* s3_Wi = (const float*)d_in[25]; const float* s3_bi = (const float*)d_in[26];
    const float* s3_Wo = (const float*)d_in[27]; const float* s3_bo = (const float*)d_in[28];
    const float* fc1W = (const float*)d_in[29]; const float* fc1b = (const float*)d_in[30];
    const float* fc3W = (const float*)d_in[31]; const float* fc3b = (const float*)d_in[32];

    size_t S = (size_t)NN * HID;
    unsigned short* xwb  = (unsigned short*)d_ws;          // NN*HID
    unsigned short* xb   = xwb + S;                        // NN*IN_DIM
    unsigned short* hb   = xb + (size_t)NN * IN_DIM;       // NN*HID
    unsigned short* aggb = hb + S;                         // NN*HID
    unsigned short* wfb  = aggb + S;                       // 10*16384
    float* dinv = (float*)(wfb + 10 * 16384);              // NN
    int*   row_start = (int*)(dinv + NN);                  // NN+1
    int*   csr_src   = row_start + NN + 1;                 // NE
    int*   gstart    = csr_src + NE;                       // NG+1
    float* gsum = (float*)(gstart + NG + 1);
    float* gsq  = gsum + HID;
    float* scl  = gsq + HID;
    float* shf  = scl + HID;
    float* pools = shf + HID;                              // 3*NG*HID
    // transient (aliased into xwb region, dead before first mgemm writes xwb)
    int* deg   = (int*)d_ws;                               // NN
    int* tmp   = (int*)d_ws + NN;                          // NN
    int* bsums = (int*)d_ws + 2 * NN;                      // NBLK

    const int TB = 256;
    const int GB2 = (NN + 127) / 128;
    const int BL  = (NN * 16 + TB - 1) / TB;     // bn_apply ushort8 blocks
    const int EB  = (NE + TB - 1) / TB;
    const int NB  = (NN + TB - 1) / TB;
    const int AGB = (NN + 7) / 8;
    const int CV  = (NN * 16 + TB - 1) / TB;     // x cvt float4 blocks

    // frag-layout weight slots
    unsigned short* wfW1   = wfb + 0 * 16384;
    unsigned short* wfS1p  = wfb + 1 * 16384;
    unsigned short* wfS1i  = wfb + 2 * 16384;
    unsigned short* wfS1o  = wfb + 3 * 16384;
    unsigned short* wfW2   = wfb + 4 * 16384;
    unsigned short* wfS2i  = wfb + 5 * 16384;
    unsigned short* wfS2o  = wfb + 6 * 16384;
    unsigned short* wfW3   = wfb + 7 * 16384;
    unsigned short* wfS3i  = wfb + 8 * 16384;
    unsigned short* wfS3o  = wfb + 9 * 16384;

    WPack wp;
    wp.w[0] = W1;    wp.K[0] = IN_DIM;
    wp.w[1] = s1_Wp; wp.K[1] = IN_DIM;
    wp.w[2] = s1_Wi; wp.K[2] = HID;
    wp.w[3] = s1_Wo; wp.K[3] = HID;
    wp.w[4] = W2;    wp.K[4] = HID;
    wp.w[5] = s2_Wi; wp.K[5] = HID;
    wp.w[6] = s2_Wo; wp.K[6] = HID;
    wp.w[7] = W3;    wp.K[7] = HID;
    wp.w[8] = s3_Wi; wp.K[8] = HID;
    wp.w[9] = s3_Wo; wp.K[9] = HID;

    // ---- CSR build + graph offsets + conversions ----
    hipMemsetAsync(deg, 0, 2 * NN * sizeof(int), stream);
    deg_kernel<<<EB, TB, 0, stream>>>(dst, deg);
    dinv_kernel<<<NB, TB, 0, stream>>>(deg, dinv);
    scan1_kernel<<<NBLK, SCAN_B, 0, stream>>>(deg, row_start, bsums);
    scan2_kernel<<<1, 512, 0, stream>>>(bsums);
    scan3_kernel<<<NB, TB, 0, stream>>>(row_start, bsums);
    fill_kernel<<<EB, TB, 0, stream>>>(src, dst, row_start, tmp, csr_src);
    gstart_kernel<<<NB, TB, 0, stream>>>(batch, gstart);
    cvt_bf16_kernel<<<CV, TB, 0, stream>>>(x, xb, NN * 16);
    wprep_kernel<<<dim3(64, 10), TB, 0, stream>>>(wp, wfb);

    // ---- layer 1 ----
    mgemm_kernel<<<GB2, TB, 0, stream>>>(xb, wfW1, IN_DIM, nullptr, nullptr, 0,
                                         nullptr, nullptr, nullptr, xwb, 2);
    mgemm_kernel<<<GB2, TB, 0, stream>>>(xb, wfS1p, IN_DIM, nullptr, nullptr, 0,
                                         nullptr, nullptr, nullptr, hb, 2);   // in_x
    gather_kernel<<<AGB, TB, 0, stream>>>(row_start, csr_src, xwb, dinv, b1, aggb);
    hipMemsetAsync(gsum, 0, 2 * HID * sizeof(float), stream);
    bn_stats_kernel<<<1024, TB, 0, stream>>>(aggb, gsum, gsq);
    bn_finalize_kernel<<<1, HID, 0, stream>>>(gsum, gsq, g1, be1, scl, shf);
    bn_apply_relu_kernel<<<BL, TB, 0, stream>>>(aggb, scl, shf);
    mgemm_kernel<<<GB2, TB, 0, stream>>>(aggb, wfS1o, HID, hb, wfS1i, HID,
                                         s1_bo, s1_bi, aggb, hb, 1);
    pool_kernel<<<NG, TB, 0, stream>>>(hb, gstart, pools);

    // ---- layer 2 ----
    mgemm_kernel<<<GB2, TB, 0, stream>>>(hb, wfW2, HID, nullptr, nullptr, 0,
                                         nullptr, nullptr, nullptr, xwb, 2);
    gather_kernel<<<AGB, TB, 0, stream>>>(row_start, csr_src, xwb, dinv, b2, aggb);
    hipMemsetAsync(gsum, 0, 2 * HID * sizeof(float), stream);
    bn_stats_kernel<<<1024, TB, 0, stream>>>(aggb, gsum, gsq);
    bn_finalize_kernel<<<1, HID, 0, stream>>>(gsum, gsq, g2, be2, scl, shf);
    bn_apply_relu_kernel<<<BL, TB, 0, stream>>>(aggb, scl, shf);
    mgemm_kernel<<<GB2, TB, 0, stream>>>(aggb, wfS2o, HID, hb, wfS2i, HID,
                                         s2_bo, s2_bi, aggb, hb, 1);
    pool_kernel<<<NG, TB, 0, stream>>>(hb, gstart, pools + (size_t)NG * HID);

    // ---- layer 3 ----
    mgemm_kernel<<<GB2, TB, 0, stream>>>(hb, wfW3, HID, nullptr, nullptr, 0,
                                         nullptr, nullptr, nullptr, xwb, 2);
    gather_kernel<<<AGB, TB, 0, stream>>>(row_start, csr_src, xwb, dinv, b3, aggb);
    hipMemsetAsync(gsum, 0, 2 * HID * sizeof(float), stream);
    bn_stats_kernel<<<1024, TB, 0, stream>>>(aggb, gsum, gsq);
    bn_finalize_kernel<<<1, HID, 0, stream>>>(gsum, gsq, g3, be3, scl, shf);
    bn_apply_relu_kernel<<<BL, TB, 0, stream>>>(aggb, scl, shf);
    mgemm_kernel<<<GB2, TB, 0, stream>>>(aggb, wfS3o, HID, hb, wfS3i, HID,
                                         s3_bo, s3_bi, aggb, hb, 1);
    pool_kernel<<<NG, TB, 0, stream>>>(hb, gstart, pools + 2 * (size_t)NG * HID);

    // ---- head ----
    head_kernel<<<NG, HID, 0, stream>>>(pools, pools + (size_t)NG * HID,
                                        pools + 2 * (size_t)NG * HID, eF,
                                        fc1W, fc1b, fc3W, fc3b, (float*)d_out);
}

// Round 6
// 860.538 us; speedup vs baseline: 11.2576x; 1.0448x over previous
//
#include <hip/hip_runtime.h>
#include <math.h>

#define NN 100000
#define NE 1600000
#define NG 1000
#define IN_DIM 64
#define HID 128
#define EXD 32
#define OUTD 10
#define BN_EPS 1e-5f

#define SCAN_B 256
#define NBLK ((NN + SCAN_B - 1) / SCAN_B)   // 391

// XCD-partitioned edge processing: 8 dst ranges x FCH edge chunks
#define FCH 128
#define FCE (NE / FCH)          // 12500 edges per chunk
#define PR  ((NN + 7) / 8)      // 12500 nodes per part

typedef __attribute__((ext_vector_type(8))) short bf16x8;
typedef __attribute__((ext_vector_type(4))) float f32x4;

__device__ __forceinline__ float bf2f(unsigned short h) {
    return __uint_as_float((unsigned int)h << 16);
}
__device__ __forceinline__ unsigned short f2bf(float f) {
    unsigned int u = __float_as_uint(f);
    u += 0x7fffu + ((u >> 16) & 1u);        // round to nearest even
    return (unsigned short)(u >> 16);
}

// ---------------- degree / CSR build (layer-invariant) ----------------
// XCD-partitioned: block b handles dst range [(b&7)*PR, ...) so each deg/csr
// cacheline is dirtied by one XCD only (L2s are per-XCD, non-coherent).

__global__ void deg_kernel(const int* __restrict__ dst, int* __restrict__ deg) {
    int part = blockIdx.x & 7;
    int lo = part * PR, hi = min(lo + PR, NN);
    int e0 = (blockIdx.x >> 3) * FCE;
    for (int e = e0 + threadIdx.x; e < e0 + FCE; e += 256) {
        int d = dst[e];
        if (d >= lo && d < hi) atomicAdd(&deg[d], 1);
    }
}

// exclusive scan of deg -> row_start; also dinv = rsqrt(deg+1)
__global__ void scan1_kernel(const int* __restrict__ deg, int* __restrict__ row_start,
                             int* __restrict__ bsums, float* __restrict__ dinv) {
    __shared__ int s[SCAN_B];
    int t = threadIdx.x;
    int i = blockIdx.x * SCAN_B + t;
    int v = (i < NN) ? deg[i] : 0;
    if (i < NN) dinv[i] = rsqrtf((float)v + 1.0f);   // +1 self loop
    s[t] = v;
    __syncthreads();
    for (int off = 1; off < SCAN_B; off <<= 1) {
        int u = (t >= off) ? s[t - off] : 0;
        __syncthreads();
        s[t] += u;
        __syncthreads();
    }
    if (i < NN) row_start[i] = s[t] - v;
    if (t == SCAN_B - 1) bsums[blockIdx.x] = s[t];
}

__global__ void scan2_kernel(int* __restrict__ bsums) {
    __shared__ int s[512];
    int t = threadIdx.x;
    int v = (t < NBLK) ? bsums[t] : 0;
    s[t] = v;
    __syncthreads();
    for (int off = 1; off < 512; off <<= 1) {
        int u = (t >= off) ? s[t - off] : 0;
        __syncthreads();
        s[t] += u;
        __syncthreads();
    }
    if (t < NBLK) bsums[t] = s[t] - v;
}

__global__ void scan3_kernel(int* __restrict__ row_start, const int* __restrict__ bsums) {
    int i = blockIdx.x * 256 + threadIdx.x;
    if (i < NN) row_start[i] += bsums[i >> 8];
    if (i == 0) row_start[NN] = NE;
}

// place each edge into its dst bucket; XCD-partitioned like deg_kernel
__global__ void fill_kernel(const int* __restrict__ src, const int* __restrict__ dst,
                            const int* __restrict__ row_start,
                            int* __restrict__ tmp, int* __restrict__ csr_src) {
    int part = blockIdx.x & 7;
    int lo = part * PR, hi = min(lo + PR, NN);
    int e0 = (blockIdx.x >> 3) * FCE;
    for (int e = e0 + threadIdx.x; e < e0 + FCE; e += 256) {
        int d = dst[e];
        if (d >= lo && d < hi) {
            int p = atomicAdd(&tmp[d], 1);
            csr_src[row_start[d] + p] = src[e];
        }
    }
}

__global__ void gstart_kernel(const int* __restrict__ batch, int* __restrict__ gstart) {
    int n = blockIdx.x * 256 + threadIdx.x;
    if (n >= NN) return;
    int bc = batch[n];
    int bp = (n == 0) ? -1 : batch[n - 1];
    for (int g = bp + 1; g <= bc; ++g) gstart[g] = n;
    if (n == NN - 1)
        for (int g = bc + 1; g <= NG; ++g) gstart[g] = NN;
}

// ---------------- f32 -> bf16 conversion (input x) ----------------

__global__ void cvt_bf16_kernel(const float* __restrict__ in, unsigned short* __restrict__ out,
                                int n4) {
    int i = blockIdx.x * 256 + threadIdx.x;
    if (i >= n4) return;
    float4 v = ((const float4*)in)[i];
    ushort4 o;
    o.x = f2bf(v.x); o.y = f2bf(v.y); o.z = f2bf(v.z); o.w = f2bf(v.w);
    ((ushort4*)out)[i] = o;
}

// ---------------- weight prep: f32 -> bf16 frag layout ----------------
// wf[m*16384 + ((k>>3)*128 + n)*8 + (k&7)]
struct WPack {
    const float* w[10];
    int K[10];
};

__global__ void wprep_kernel(WPack p, unsigned short* __restrict__ wf) {
    int m = blockIdx.y;
    int idx = blockIdx.x * 256 + threadIdx.x;
    int K = p.K[m];
    if (idx >= K * 128) return;
    int k = idx >> 7, n = idx & 127;
    wf[m * 16384 + (((k >> 3) * 128 + n) << 3) + (k & 7)] = f2bf(p.w[m][idx]);
}

// ---------------- GCN aggregation: pull-gather, bf16 rows, bf16 out ----------------
// 8 nodes per block, 32 lanes per node, lane covers feats [4*lane .. 4*lane+3]
__launch_bounds__(256)
__global__ void gather_kernel(const int* __restrict__ row_start,
                              const int* __restrict__ csr_src,
                              const unsigned short* __restrict__ xwb,
                              const float* __restrict__ dinv,
                              const float* __restrict__ b,
                              unsigned short* __restrict__ aggb) {
    int node = blockIdx.x * 8 + (threadIdx.x >> 5);
    int lane = threadIdx.x & 31;
    if (node >= NN) return;
    int rs = row_start[node], re = row_start[node + 1];
    float d = dinv[node];
    int fo = lane << 2;
    ushort4 sv = *(const ushort4*)(xwb + (size_t)node * HID + fo);
    float4 accE = make_float4(0.f, 0.f, 0.f, 0.f);
    int e = rs;
    for (; e + 3 < re; e += 4) {
        int s0 = csr_src[e], s1 = csr_src[e + 1], s2 = csr_src[e + 2], s3 = csr_src[e + 3];
        float c0 = dinv[s0], c1 = dinv[s1], c2 = dinv[s2], c3 = dinv[s3];
        ushort4 r0 = *(const ushort4*)(xwb + (size_t)s0 * HID + fo);
        ushort4 r1 = *(const ushort4*)(xwb + (size_t)s1 * HID + fo);
        ushort4 r2 = *(const ushort4*)(xwb + (size_t)s2 * HID + fo);
        ushort4 r3 = *(const ushort4*)(xwb + (size_t)s3 * HID + fo);
        accE.x += c0 * bf2f(r0.x) + c1 * bf2f(r1.x) + c2 * bf2f(r2.x) + c3 * bf2f(r3.x);
        accE.y += c0 * bf2f(r0.y) + c1 * bf2f(r1.y) + c2 * bf2f(r2.y) + c3 * bf2f(r3.y);
        accE.z += c0 * bf2f(r0.z) + c1 * bf2f(r1.z) + c2 * bf2f(r2.z) + c3 * bf2f(r3.z);
        accE.w += c0 * bf2f(r0.w) + c1 * bf2f(r1.w) + c2 * bf2f(r2.w) + c3 * bf2f(r3.w);
    }
    for (; e < re; ++e) {
        int s0 = csr_src[e];
        float c0 = dinv[s0];
        ushort4 r0 = *(const ushort4*)(xwb + (size_t)s0 * HID + fo);
        accE.x += c0 * bf2f(r0.x);
        accE.y += c0 * bf2f(r0.y);
        accE.z += c0 * bf2f(r0.z);
        accE.w += c0 * bf2f(r0.w);
    }
    float d2 = d * d;
    ushort4 o;
    o.x = f2bf(d * accE.x + d2 * bf2f(sv.x) + b[fo + 0]);
    o.y = f2bf(d * accE.y + d2 * bf2f(sv.y) + b[fo + 1]);
    o.z = f2bf(d * accE.z + d2 * bf2f(sv.z) + b[fo + 2]);
    o.w = f2bf(d * accE.w + d2 * bf2f(sv.w) + b[fo + 3]);
    *(ushort4*)(aggb + (size_t)node * HID + fo) = o;
}

// ---------------- BatchNorm (bf16 agg) ----------------

__global__ void bn_stats_kernel(const unsigned short* __restrict__ aggb,
                                float* __restrict__ gsum, float* __restrict__ gsq) {
    __shared__ float ss[4][128], sq[4][128];
    int t = threadIdx.x;
    int fp = (t & 63) << 1;
    int sub = t >> 6;
    float s0 = 0.f, s1 = 0.f, q0 = 0.f, q1 = 0.f;
    for (int r = blockIdx.x * 4 + sub; r < NN; r += 4096) {
        unsigned int u = *(const unsigned int*)(aggb + (size_t)r * HID + fp);
        float v0 = bf2f((unsigned short)(u & 0xffffu));
        float v1 = bf2f((unsigned short)(u >> 16));
        s0 += v0; q0 += v0 * v0;
        s1 += v1; q1 += v1 * v1;
    }
    ss[sub][fp] = s0; ss[sub][fp + 1] = s1;
    sq[sub][fp] = q0; sq[sub][fp + 1] = q1;
    __syncthreads();
    if (t < 128) {
        atomicAdd(&gsum[t], ss[0][t] + ss[1][t] + ss[2][t] + ss[3][t]);
        atomicAdd(&gsq[t],  sq[0][t] + sq[1][t] + sq[2][t] + sq[3][t]);
    }
}

__global__ void bn_finalize_kernel(const float* __restrict__ gsum, const float* __restrict__ gsq,
                                   const float* __restrict__ g, const float* __restrict__ be,
                                   float* __restrict__ scale, float* __restrict__ shift) {
    int f = threadIdx.x;
    float mu = gsum[f] * (1.0f / NN);
    float var = gsq[f] * (1.0f / NN) - mu * mu;
    float sc = g[f] * rsqrtf(var + BN_EPS);
    scale[f] = sc;
    shift[f] = be[f] - mu * sc;
}

__global__ void bn_apply_relu_kernel(unsigned short* __restrict__ aggb,
                                     const float* __restrict__ scale,
                                     const float* __restrict__ shift) {
    int i = blockIdx.x * 256 + threadIdx.x;
    if (i >= NN * 16) return;
    int c = (i & 15) << 3;
    bf16x8 v = ((const bf16x8*)aggb)[i];
    bf16x8 o;
#pragma unroll
    for (int j = 0; j < 8; ++j)
        o[j] = (short)f2bf(fmaxf(bf2f((unsigned short)v[j]) * scale[c + j] + shift[c + j], 0.f));
    ((bf16x8*)aggb)[i] = o;
}

// ---------------- MFMA GEMM (bf16 in, f32 acc, bf16 out) ----------------
// Block: 256 thr / 4 waves; tile 128 rows x 128 cols; wave owns 32 rows in K-loop.
// B-frags read directly from pre-transformed global wf (L2-hot). No LDS in K-loop.
// Epilogue stages C tile in LDS (bf16, padded stride) for coalesced 16B global I/O.
// __launch_bounds__(256,4): 4 blocks/CU so all 782 blocks are co-resident.
#define CS_STRIDE 136
__launch_bounds__(256, 4)
__global__ void mgemm_kernel(const unsigned short* __restrict__ A1,
                             const unsigned short* __restrict__ wfA, int K1,
                             const unsigned short* A2,
                             const unsigned short* __restrict__ wfB, int K2,
                             const float* __restrict__ bias1, const float* __restrict__ bias2,
                             const unsigned short* outx,
                             unsigned short* target, int mode) {
    __shared__ unsigned short cs[128 * CS_STRIDE];
    int tid = threadIdx.x;
    int lane = tid & 63;
    int wv = tid >> 6;
    int lane15 = lane & 15;
    int q = lane >> 4;
    int m0 = blockIdx.x * 128 + wv * 32;

    f32x4 acc[2][8];
#pragma unroll
    for (int r = 0; r < 2; ++r)
#pragma unroll
        for (int nt = 0; nt < 8; ++nt)
            acc[r][nt] = (f32x4){0.f, 0.f, 0.f, 0.f};

    bf16x8 zf = {0, 0, 0, 0, 0, 0, 0, 0};

    for (int p = 0; p < 2; ++p) {
        const unsigned short* A = p ? A2 : A1;
        const unsigned short* wf = p ? wfB : wfA;
        int K = p ? K2 : K1;
        if (K == 0) continue;
        int row0 = m0 + lane15;
        const unsigned short* a0p = A + (size_t)row0 * K + (q << 3);
        const unsigned short* a1p = a0p + (size_t)16 * K;
        bool g0 = row0 < NN, g1 = (row0 + 16) < NN;
#pragma unroll 4
        for (int k0 = 0; k0 < K; k0 += 32) {
            bf16x8 af0 = zf, af1 = zf;
            if (g0) af0 = *(const bf16x8*)(a0p + k0);
            if (g1) af1 = *(const bf16x8*)(a1p + k0);
            const unsigned short* wb = wf + (((k0 >> 3) + q) << 10) + (lane15 << 3);
#pragma unroll
            for (int nt = 0; nt < 8; ++nt) {
                bf16x8 bf = *(const bf16x8*)(wb + nt * 128);
                acc[0][nt] = __builtin_amdgcn_mfma_f32_16x16x32_bf16(af0, bf, acc[0][nt], 0, 0, 0);
                acc[1][nt] = __builtin_amdgcn_mfma_f32_16x16x32_bf16(af1, bf, acc[1][nt], 0, 0, 0);
            }
        }
    }

    // ---- stage C tile into LDS (C/D layout: col=lane15, row=q*4+g) ----
    if (mode == 1) {
        float bsum[8];
#pragma unroll
        for (int nt = 0; nt < 8; ++nt)
            bsum[nt] = bias1[nt * 16 + lane15] + bias2[nt * 16 + lane15];
#pragma unroll
        for (int r = 0; r < 2; ++r)
#pragma unroll
            for (int nt = 0; nt < 8; ++nt)
#pragma unroll
                for (int g = 0; g < 4; ++g) {
                    int rr = wv * 32 + r * 16 + q * 4 + g;
                    cs[rr * CS_STRIDE + nt * 16 + lane15] = f2bf(acc[r][nt][g] + bsum[nt]);
                }
    } else {
#pragma unroll
        for (int r = 0; r < 2; ++r)
#pragma unroll
            for (int nt = 0; nt < 8; ++nt)
#pragma unroll
                for (int g = 0; g < 4; ++g) {
                    int rr = wv * 32 + r * 16 + q * 4 + g;
                    cs[rr * CS_STRIDE + nt * 16 + lane15] = f2bf(acc[r][nt][g]);
                }
    }
    __syncthreads();

    // ---- coalesced global epilogue: thread covers (row, 8-col chunk) ----
#pragma unroll
    for (int i = 0; i < 8; ++i) {
        int rt = (tid >> 4) + i * 16;
        int ch = tid & 15;
        int row = blockIdx.x * 128 + rt;
        if (row >= NN) continue;
        bf16x8 c = *(const bf16x8*)(cs + rt * CS_STRIDE + (ch << 3));
        size_t off = (size_t)row * HID + (ch << 3);
        if (mode == 1) {
            bf16x8 oxv = *(const bf16x8*)(outx + off);
            bf16x8 ixv = *(const bf16x8*)(target + off);
            bf16x8 o;
#pragma unroll
            for (int j = 0; j < 8; ++j) {
                float t = bf2f((unsigned short)c[j]);
                float z = 1.0f / (1.0f + expf(-t));
                float h = z * bf2f((unsigned short)oxv[j]) +
                          (1.0f - z) * bf2f((unsigned short)ixv[j]);
                o[j] = (short)f2bf(h);
            }
            *(bf16x8*)(target + off) = o;
        } else {
            *(bf16x8*)(target + off) = c;
        }
    }
}

// ---------------- pooling (segment-based, bf16 input) ----------------

__global__ void pool_kernel(const unsigned short* __restrict__ h,
                            const int* __restrict__ gstart,
                            float* __restrict__ pool) {
    __shared__ float red[8][128];
    int g = blockIdx.x, t = threadIdx.x;
    int lane = t & 31, sub = t >> 5;
    int s = gstart[g], e = gstart[g + 1];
    float4 acc = make_float4(0.f, 0.f, 0.f, 0.f);
    for (int r = s + sub; r < e; r += 8) {
        ushort4 v = *(const ushort4*)(h + (size_t)r * HID + (lane << 2));
        acc.x += bf2f(v.x); acc.y += bf2f(v.y);
        acc.z += bf2f(v.z); acc.w += bf2f(v.w);
    }
    *(float4*)&red[sub][lane << 2] = acc;
    __syncthreads();
    if (t < 128) {
        float a = 0.f;
#pragma unroll
        for (int i = 0; i < 8; ++i) a += red[i][t];
        pool[(size_t)g * HID + t] = a / (float)max(e - s, 1);
    }
}

// ---------------- MLP head ----------------

__global__ void head_kernel(const float* __restrict__ pool1, const float* __restrict__ pool2,
                            const float* __restrict__ pool3,
                            const float* __restrict__ eF,
                            const float* __restrict__ fc1W, const float* __restrict__ fc1b,
                            const float* __restrict__ fc3W, const float* __restrict__ fc3b,
                            float* __restrict__ out) {
    __shared__ float hg[3 * HID + EXD];
    __shared__ float hh[HID];
    int g = blockIdx.x, t = threadIdx.x;
    hg[t]           = pool1[(size_t)g * HID + t];
    hg[HID + t]     = pool2[(size_t)g * HID + t];
    hg[2 * HID + t] = pool3[(size_t)g * HID + t];
    if (t < EXD) hg[3 * HID + t] = eF[(size_t)g * EXD + t];
    __syncthreads();
    float acc = fc1b[t];
    for (int k = 0; k < 3 * HID + EXD; ++k) acc += hg[k] * fc1W[(size_t)k * HID + t];
    hh[t] = fmaxf(acc, 0.f);
    __syncthreads();
    if (t < OUTD) {
        float a2 = fc3b[t];
        for (int k = 0; k < HID; ++k) a2 += hh[k] * fc3W[(size_t)k * OUTD + t];
        out[(size_t)g * OUTD + t] = a2;
    }
}

// ---------------- launch ----------------

extern "C" void kernel_launch(void* const* d_in, const int* in_sizes, int n_in,
                              void* d_out, int out_size, void* d_ws, size_t ws_size,
                              hipStream_t stream) {
    const float* x      = (const float*)d_in[0];
    const float* eF     = (const float*)d_in[1];
    const int*   ei     = (const int*)d_in[2];
    const int*   batch  = (const int*)d_in[3];
    const int* src = ei;
    const int* dst = ei + NE;

    const float* W1 = (const float*)d_in[4];  const float* b1 = (const float*)d_in[5];
    const float* W2 = (const float*)d_in[6];  const float* b2 = (const float*)d_in[7];
    const float* W3 = (const float*)d_in[8];  const float* b3 = (const float*)d_in[9];
    const float* g1 = (const float*)d_in[10]; const float* be1 = (const float*)d_in[11];
    const float* g2 = (const float*)d_in[12]; const float* be2 = (const float*)d_in[13];
    const float* g3 = (const float*)d_in[14]; const float* be3 = (const float*)d_in[15];
    const float* s1_Wp = (const float*)d_in[16];
    const float* s1_Wi = (const float*)d_in[17]; const float* s1_bi = (const float*)d_in[18];
    const float* s1_Wo = (const float*)d_in[19]; const float* s1_bo = (const float*)d_in[20];
    const float* s2_Wi = (const float*)d_in[21]; const float* s2_bi = (const float*)d_in[22];
    const float* s2_Wo = (const float*)d_in[23]; const float* s2_bo = (const float*)d_in[24];
    const float* s3_Wi = (const float*)d_in[25]; const float* s3_bi = (const float*)d_in[26];
    const float* s3_Wo = (const float*)d_in[27]; const float* s3_bo = (const float*)d_in[28];
    const float* fc1W = (const float*)d_in[29]; const float* fc1b = (const float*)d_in[30];
    const float* fc3W = (const float*)d_in[31]; const float* fc3b = (const float*)d_in[32];

    size_t S = (size_t)NN * HID;
    unsigned short* xwb  = (unsigned short*)d_ws;          // NN*HID
    unsigned short* xb   = xwb + S;                        // NN*IN_DIM
    unsigned short* hb   = xb + (size_t)NN * IN_DIM;       // NN*HID
    unsigned short* aggb = hb + S;                         // NN*HID
    unsigned short* wfb  = aggb + S;                       // 10*16384
    float* dinv = (float*)(wfb + 10 * 16384);              // NN
    int*   row_start = (int*)(dinv + NN);                  // NN+1
    int*   csr_src   = row_start + NN + 1;                 // NE
    int*   gstart    = csr_src + NE;                       // NG+1
    float* gsum = (float*)(gstart + NG + 1);
    float* gsq  = gsum + HID;
    float* scl  = gsq + HID;
    float* shf  = scl + HID;
    float* pools = shf + HID;                              // 3*NG*HID
    // transient (aliased into xwb region, dead before first mgemm writes xwb)
    int* deg   = (int*)d_ws;                               // NN
    int* tmp   = (int*)d_ws + NN;                          // NN
    int* bsums = (int*)d_ws + 2 * NN;                      // NBLK

    const int TB = 256;
    const int GB2 = (NN + 127) / 128;
    const int BL  = (NN * 16 + TB - 1) / TB;
    const int NB  = (NN + TB - 1) / TB;
    const int AGB = (NN + 7) / 8;
    const int CV  = (NN * 16 + TB - 1) / TB;
    const int PB  = FCH * 8;                     // partitioned edge blocks

    // frag-layout weight slots
    unsigned short* wfW1   = wfb + 0 * 16384;
    unsigned short* wfS1p  = wfb + 1 * 16384;
    unsigned short* wfS1i  = wfb + 2 * 16384;
    unsigned short* wfS1o  = wfb + 3 * 16384;
    unsigned short* wfW2   = wfb + 4 * 16384;
    unsigned short* wfS2i  = wfb + 5 * 16384;
    unsigned short* wfS2o  = wfb + 6 * 16384;
    unsigned short* wfW3   = wfb + 7 * 16384;
    unsigned short* wfS3i  = wfb + 8 * 16384;
    unsigned short* wfS3o  = wfb + 9 * 16384;

    WPack wp;
    wp.w[0] = W1;    wp.K[0] = IN_DIM;
    wp.w[1] = s1_Wp; wp.K[1] = IN_DIM;
    wp.w[2] = s1_Wi; wp.K[2] = HID;
    wp.w[3] = s1_Wo; wp.K[3] = HID;
    wp.w[4] = W2;    wp.K[4] = HID;
    wp.w[5] = s2_Wi; wp.K[5] = HID;
    wp.w[6] = s2_Wo; wp.K[6] = HID;
    wp.w[7] = W3;    wp.K[7] = HID;
    wp.w[8] = s3_Wi; wp.K[8] = HID;
    wp.w[9] = s3_Wo; wp.K[9] = HID;

    // ---- CSR build + graph offsets + conversions ----
    hipMemsetAsync(deg, 0, 2 * NN * sizeof(int), stream);
    deg_kernel<<<PB, TB, 0, stream>>>(dst, deg);
    scan1_kernel<<<NBLK, SCAN_B, 0, stream>>>(deg, row_start, bsums, dinv);
    scan2_kernel<<<1, 512, 0, stream>>>(bsums);
    scan3_kernel<<<NB, TB, 0, stream>>>(row_start, bsums);
    fill_kernel<<<PB, TB, 0, stream>>>(src, dst, row_start, tmp, csr_src);
    gstart_kernel<<<NB, TB, 0, stream>>>(batch, gstart);
    cvt_bf16_kernel<<<CV, TB, 0, stream>>>(x, xb, NN * 16);
    wprep_kernel<<<dim3(64, 10), TB, 0, stream>>>(wp, wfb);

    // ---- layer 1 ----
    mgemm_kernel<<<GB2, TB, 0, stream>>>(xb, wfW1, IN_DIM, nullptr, nullptr, 0,
                                         nullptr, nullptr, nullptr, xwb, 2);
    mgemm_kernel<<<GB2, TB, 0, stream>>>(xb, wfS1p, IN_DIM, nullptr, nullptr, 0,
                                         nullptr, nullptr, nullptr, hb, 2);   // in_x
    gather_kernel<<<AGB, TB, 0, stream>>>(row_start, csr_src, xwb, dinv, b1, aggb);
    hipMemsetAsync(gsum, 0, 2 * HID * sizeof(float), stream);
    bn_stats_kernel<<<1024, TB, 0, stream>>>(aggb, gsum, gsq);
    bn_finalize_kernel<<<1, HID, 0, stream>>>(gsum, gsq, g1, be1, scl, shf);
    bn_apply_relu_kernel<<<BL, TB, 0, stream>>>(aggb, scl, shf);
    mgemm_kernel<<<GB2, TB, 0, stream>>>(aggb, wfS1o, HID, hb, wfS1i, HID,
                                         s1_bo, s1_bi, aggb, hb, 1);
    pool_kernel<<<NG, TB, 0, stream>>>(hb, gstart, pools);

    // ---- layer 2 ----
    mgemm_kernel<<<GB2, TB, 0, stream>>>(hb, wfW2, HID, nullptr, nullptr, 0,
                                         nullptr, nullptr, nullptr, xwb, 2);
    gather_kernel<<<AGB, TB, 0, stream>>>(row_start, csr_src, xwb, dinv, b2, aggb);
    hipMemsetAsync(gsum, 0, 2 * HID * sizeof(float), stream);
    bn_stats_kernel<<<1024, TB, 0, stream>>>(aggb, gsum, gsq);
    bn_finalize_kernel<<<1, HID, 0, stream>>>(gsum, gsq, g2, be2, scl, shf);
    bn_apply_relu_kernel<<<BL, TB, 0, stream>>>(aggb, scl, shf);
    mgemm_kernel<<<GB2, TB, 0, stream>>>(aggb, wfS2o, HID, hb, wfS2i, HID,
                                         s2_bo, s2_bi, aggb, hb, 1);
    pool_kernel<<<NG, TB, 0, stream>>>(hb, gstart, pools + (size_t)NG * HID);

    // ---- layer 3 ----
    mgemm_kernel<<<GB2, TB, 0, stream>>>(hb, wfW3, HID, nullptr, nullptr, 0,
                                         nullptr, nullptr, nullptr, xwb, 2);
    gather_kernel<<<AGB, TB, 0, stream>>>(row_start, csr_src, xwb, dinv, b3, aggb);
    hipMemsetAsync(gsum, 0, 2 * HID * sizeof(float), stream);
    bn_stats_kernel<<<1024, TB, 0, stream>>>(aggb, gsum, gsq);
    bn_finalize_kernel<<<1, HID, 0, stream>>>(gsum, gsq, g3, be3, scl, shf);
    bn_apply_relu_kernel<<<BL, TB, 0, stream>>>(aggb, scl, shf);
    mgemm_kernel<<<GB2, TB, 0, stream>>>(aggb, wfS3o, HID, hb, wfS3i, HID,
                                         s3_bo, s3_bi, aggb, hb, 1);
    pool_kernel<<<NG, TB, 0, stream>>>(hb, gstart, pools + 2 * (size_t)NG * HID);

    // ---- head ----
    head_kernel<<<NG, HID, 0, stream>>>(pools, pools + (size_t)NG * HID,
                                        pools + 2 * (size_t)NG * HID, eF,
                                        fc1W, fc1b, fc3W, fc3b, (float*)d_out);
}